// Round 7
// baseline (320.275 us; speedup 1.0000x reference)
//
#include <hip/hip_runtime.h>

typedef unsigned short u16;
typedef float f4 __attribute__((ext_vector_type(4)));
typedef u16 u16x8 __attribute__((ext_vector_type(8)));
typedef _Float16 half2 __attribute__((ext_vector_type(2)));

// ---------- bf16 helpers ----------
static __device__ __forceinline__ float bf2f(u16 u) {
    union { unsigned int i; float f; } v;
    v.i = ((unsigned int)u) << 16;
    return v.f;
}
static __device__ __forceinline__ u16 f2bf(float f) {
    union { float f; unsigned int i; } v;
    v.f = f;
    unsigned int x = v.i;
    x += 0x7fffu + ((x >> 16) & 1u);   // RNE
    return (u16)(x >> 16);
}
// dtype-flexible load: dt==0 -> bf16, dt==1 -> f32
static __device__ __forceinline__ float gld(int dt, const void* p, int i) {
    return dt ? ((const float*)p)[i] : bf2f(((const u16*)p)[i]);
}

// per-wave dtype detect from first 64 u16s of coords (no global flag)
static __device__ __forceinline__ int detect_dt(const void* coords) {
    u16 v = ((const u16*)coords)[threadIdx.x & 63];
    int e = (v >> 7) & 0xFF;
    bool inr = (e >= 90) && (e <= 126);
    unsigned long long m = __ballot(inr);
    return (__popcll(m) >= 56) ? 0 : 1;   // 0=bf16, 1=f32
}

// f16 pair dot: full-rate v_dot2_f32_f16 when available
#if __has_builtin(__builtin_amdgcn_fdot2)
static __device__ __forceinline__ float FDOT2(half2 a, half2 b, float c) {
    return __builtin_amdgcn_fdot2(a, b, c, false);
}
#else
static __device__ __forceinline__ float FDOT2(half2 a, half2 b, float c) {
    return fmaf((float)a[0], (float)b[0], fmaf((float)a[1], (float)b[1], c));
}
#endif
static __device__ __forceinline__ half2 pk(float a, float b) {
    return __builtin_bit_cast(half2, __builtin_amdgcn_cvt_pkrtz(a, b));
}

// ---------- ws layout (bytes) ----------
#define WF_OFF        64u            // 4449 u32 = 17796 B
#define PLANES_S_OFF  34304u         // 3*524288 u16 = 3145728 B
#define VOL_S_OFF     3180032u       // 2097152 u16  = 4194304 B
#define LINES_S_OFF   7374336u       // 12288 u16    = 24576 B
#define PART_OFF      7398912u       // 32*4096 u32  = 524288 B
#define OFFS_OFF      7923200u       // 4096 u32     = 16384 B
#define ORDER_OFF     7939584u       // 4*M

#define NBUCK 4096
#define HBLOCKS 32

// weight region (4-byte units):
//   Wph[3*512] h2 | bv[96] f32 | W1ph[2560] h2 | b1v[128] | W2v[128] | b2v[1]

// =====================================================================
// spatial key
// =====================================================================
static __device__ __forceinline__ int make_key(int dt, const void* coords, int p) {
    float x = gld(dt, coords, p * 3 + 0);
    float y = gld(dt, coords, p * 3 + 1);
    float z = gld(dt, coords, p * 3 + 2);
    int kx = min(max((int)((x + 1.0f) * 8.0f), 0), 15);
    int ky = min(max((int)((y + 1.0f) * 8.0f), 0), 15);
    int kz = min(max((int)((z + 1.0f) * 8.0f), 0), 15);
    return (kz * 16 + ky) * 16 + kx;
}

// =====================================================================
// weight packing work (shared by fused prep + fallback)
// =====================================================================
static __device__ __forceinline__ void weights_work(
    int dt, int r,
    const void* Wx, const void* bx, const void* Wy, const void* by,
    const void* Wz, const void* bz, const void* W1, const void* b1,
    const void* W2, const void* b2, float* wbase)
{
    half2* Wph  = (half2*)wbase;            // 1536: [3][16 kp][32 o]
    float* bv   = wbase + 1536;             // 96
    half2* W1ph = (half2*)(wbase + 1632);   // 2560: [128 j][20 ip]
    float* b1v  = wbase + 4192;             // 128
    float* W2v  = wbase + 4320;             // 128
    float* b2v  = wbase + 4448;             // 1
    if (r < 1536) {
        int m = r >> 9, idx = r & 511;
        int kp = idx >> 5, o = idx & 31;
        const void* s = (m == 0) ? Wx : (m == 1) ? Wy : Wz;
        float f0 = gld(dt, s, (2 * kp) * 32 + o);
        float f1 = gld(dt, s, (2 * kp + 1) * 32 + o);
        Wph[r] = pk(f0, f1);
    } else if (r < 1632) {
        int q = r - 1536;
        int m = q >> 5, c = q & 31;
        const void* s = (m == 0) ? bx : (m == 1) ? by : bz;
        bv[q] = gld(dt, s, c);
    } else if (r < 4192) {
        int q = r - 1632;                      // q = j*20+ip
        int j = q / 20, ip = q - j * 20;
        float f0 = gld(dt, W1, (2 * ip) * 128 + j);
        float f1 = gld(dt, W1, (2 * ip + 1) * 128 + j);
        W1ph[q] = pk(f0, f1);
    } else if (r < 4320) {
        b1v[r - 4192] = gld(dt, b1, r - 4192);
    } else if (r < 4448) {
        W2v[r - 4320] = gld(dt, W2, r - 4320);
    } else if (r == 4448) {
        b2v[0] = gld(dt, b2, 0);
    }
}

// =====================================================================
// fused prep: grid transpose (blocks 0..1797) + weights (1798..1815)
//           + histogram partials, plain stores (1816..1847)
// =====================================================================
__global__ __launch_bounds__(256) void kp_prep_all(
    const void* __restrict__ coords,
    const void* __restrict__ lx, const void* __restrict__ ly,
    const void* __restrict__ lz,
    const void* __restrict__ pxy, const void* __restrict__ pyz,
    const void* __restrict__ pxz, const void* __restrict__ vol,
    const void* __restrict__ Wx, const void* __restrict__ bx,
    const void* __restrict__ Wy, const void* __restrict__ by,
    const void* __restrict__ Wz, const void* __restrict__ bz,
    const void* __restrict__ W1, const void* __restrict__ b1,
    const void* __restrict__ W2, const void* __restrict__ b2,
    float* __restrict__ wbase,
    u16* __restrict__ planes_s, u16* __restrict__ vol_s,
    u16* __restrict__ lines_s, unsigned int* __restrict__ part, int M)
{
    __shared__ unsigned int lh[NBUCK];
    int dt = detect_dt(coords);
    int blk = blockIdx.x;
    if (blk < 1798) {
        int t = blk * 256 + threadIdx.x;   // [0, 460288)
        u16x8 v;
        if (t < 196608) {                 // planes: 8 consecutive out u16
            int o = t * 8;
            int pl = o >> 19;
            int r  = o & 524287;
            int pos = r >> 5, c0 = r & 31;        // c0 in {0,8,16,24}
            const void* src = (pl == 0) ? pxy : (pl == 1) ? pyz : pxz;
#pragma unroll
            for (int i = 0; i < 8; ++i)
                v[i] = dt ? f2bf(((const float*)src)[(c0 + i) * 16384 + pos])
                          : ((const u16*)src)[(c0 + i) * 16384 + pos];
            *(u16x8*)(planes_s + o) = v;
        } else if (t < 458752) {          // volume: thread = one pos, 8 channels
            int pos = t - 196608;         // < 262144
#pragma unroll
            for (int c = 0; c < 8; ++c)
                v[c] = dt ? f2bf(((const float*)vol)[c * 262144 + pos])
                          : ((const u16*)vol)[c * 262144 + pos];
            *(u16x8*)(vol_s + pos * 8) = v;
        } else {                          // lines
            int o = (t - 458752) * 8;     // < 12288
            int l = o >> 12, rr = o & 4095;
            int pos = rr >> 5, c0 = rr & 31;
            const void* src = (l == 0) ? lx : (l == 1) ? ly : lz;
#pragma unroll
            for (int i = 0; i < 8; ++i)
                v[i] = dt ? f2bf(((const float*)src)[(c0 + i) * 128 + pos])
                          : ((const u16*)src)[(c0 + i) * 128 + pos];
            *(u16x8*)(lines_s + o) = v;
        }
    } else if (blk < 1816) {
        int r = (blk - 1798) * 256 + threadIdx.x;   // [0, 4608)
        weights_work(dt, r, Wx, bx, Wy, by, Wz, bz, W1, b1, W2, b2, wbase);
    } else {
        int b = blk - 1816;               // [0, 32)
        for (int i = threadIdx.x; i < NBUCK; i += 256) lh[i] = 0u;
        __syncthreads();
        for (int p = b * 256 + threadIdx.x; p < M; p += HBLOCKS * 256)
            atomicAdd(&lh[make_key(dt, coords, p)], 1u);
        __syncthreads();
        for (int i = threadIdx.x; i < NBUCK; i += 256)
            part[b * NBUCK + i] = lh[i];          // plain store, no init needed
    }
}

// =====================================================================
// scan: offs = exclusive prefix of column-sums of part
// =====================================================================
__global__ __launch_bounds__(256) void kp_scan(
    const unsigned int* __restrict__ part, unsigned int* __restrict__ offs)
{
    __shared__ unsigned int psum[256];
    int t = threadIdx.x;
    unsigned int bs[16];
    unsigned int s = 0;
#pragma unroll
    for (int i = 0; i < 16; ++i) {
        int bkt = t * 16 + i;
        unsigned int v = 0;
#pragma unroll
        for (int k = 0; k < HBLOCKS; ++k) v += part[k * NBUCK + bkt];
        bs[i] = v; s += v;
    }
    psum[t] = s;
    __syncthreads();
    if (t == 0) {
        unsigned int run = 0;
        for (int i = 0; i < 256; ++i) { unsigned int v = psum[i]; psum[i] = run; run += v; }
    }
    __syncthreads();
    unsigned int run = psum[t];
#pragma unroll
    for (int i = 0; i < 16; ++i) { offs[t * 16 + i] = run; run += bs[i]; }
}

// =====================================================================
// scatter: order[] permutation
// =====================================================================
__global__ __launch_bounds__(256) void kp_scatter(
    const void* __restrict__ coords,
    unsigned int* __restrict__ offs, int* __restrict__ order, int M)
{
    int dt = detect_dt(coords);
    int stride = gridDim.x * 256;
    for (int p = blockIdx.x * 256 + threadIdx.x; p < M; p += stride) {
        int key = make_key(dt, coords, p);
        unsigned int pos = atomicAdd(&offs[key], 1u);
        order[pos] = p;
    }
}

// =====================================================================
// shared math
// =====================================================================
struct Samp { int i0, i1; float w0, w1; };

static __device__ __forceinline__ Samp make_samp(float g, int N) {
    float ix = (g + 1.0f) * 0.5f * (float)(N - 1);
    float fl = floorf(ix);
    float w  = ix - fl;
    int i  = (int)fl;
    int i1 = i + 1;
    float v0 = (i  >= 0 && i  < N) ? 1.0f : 0.0f;
    float v1 = (i1 >= 0 && i1 < N) ? 1.0f : 0.0f;
    Samp s;
    s.w0 = (1.0f - w) * v0;
    s.w1 = w * v1;
    s.i0 = min(max(i, 0), N - 1);
    s.i1 = min(max(i1, 0), N - 1);
    return s;
}

// fused term with f16 dot2: feat[o] += phi_line[o] * phi_plane[o]
static __device__ __forceinline__ void term_fused(
    const u16* __restrict__ Ls, const Samp& sl,
    const u16* __restrict__ Ps, const Samp& sa, const Samp& sb,
    const half2* __restrict__ Wp, const float* __restrict__ b,
    float (&feat)[40])
{
    float ta[32], tb[32];
#pragma unroll
    for (int o = 0; o < 32; ++o) { ta[o] = b[o]; tb[o] = b[o]; }
    const u16x8* l0  = (const u16x8*)(Ls + sl.i0 * 32);
    const u16x8* l1  = (const u16x8*)(Ls + sl.i1 * 32);
    const u16x8* p00 = (const u16x8*)(Ps + (sb.i0 * 128 + sa.i0) * 32);
    const u16x8* p01 = (const u16x8*)(Ps + (sb.i0 * 128 + sa.i1) * 32);
    const u16x8* p10 = (const u16x8*)(Ps + (sb.i1 * 128 + sa.i0) * 32);
    const u16x8* p11 = (const u16x8*)(Ps + (sb.i1 * 128 + sa.i1) * 32);
    float w00 = sb.w0 * sa.w0, w01 = sb.w0 * sa.w1;
    float w10 = sb.w1 * sa.w0, w11 = sb.w1 * sa.w1;
#pragma unroll 1
    for (int cc = 0; cc < 4; ++cc) {
        u16x8 A0 = l0[cc], A1 = l1[cc];
        u16x8 Q00 = p00[cc], Q01 = p01[cc], Q10 = p10[cc], Q11 = p11[cc];
#pragma unroll
        for (int kk = 0; kk < 4; ++kk) {
            int k0 = 2 * kk, k1 = 2 * kk + 1;
            float el0 = sl.w0 * bf2f(A0[k0]) + sl.w1 * bf2f(A1[k0]);
            float el1 = sl.w0 * bf2f(A0[k1]) + sl.w1 * bf2f(A1[k1]);
            float ep0 = w00 * bf2f(Q00[k0]) + w01 * bf2f(Q01[k0])
                      + w10 * bf2f(Q10[k0]) + w11 * bf2f(Q11[k0]);
            float ep1 = w00 * bf2f(Q00[k1]) + w01 * bf2f(Q01[k1])
                      + w10 * bf2f(Q10[k1]) + w11 * bf2f(Q11[k1]);
            half2 r1 = pk(fmaxf(el0, 0.0f), fmaxf(el1, 0.0f));
            half2 r2 = pk(fmaxf(ep0, 0.0f), fmaxf(ep1, 0.0f));
            const half2* wr = Wp + (cc * 4 + kk) * 32;
#pragma unroll
            for (int o = 0; o < 32; ++o) {
                half2 w = wr[o];
                ta[o] = FDOT2(r1, w, ta[o]);
                tb[o] = FDOT2(r2, w, tb[o]);
            }
        }
    }
#pragma unroll
    for (int o = 0; o < 32; ++o) feat[o] = fmaf(ta[o], tb[o], feat[o]);
}

static __device__ __forceinline__ float head_mlp(
    const float (&feat)[40], const half2* __restrict__ W1ph,
    const float* __restrict__ b1v, const float* __restrict__ W2v,
    const float* __restrict__ b2v)
{
    half2 fp[20];
#pragma unroll
    for (int ip = 0; ip < 20; ++ip) fp[ip] = pk(feat[2 * ip], feat[2 * ip + 1]);
    float acc_out = b2v[0];
#pragma unroll 2
    for (int j = 0; j < 128; ++j) {
        float acc = b1v[j];
        const half2* wr = W1ph + j * 20;
#pragma unroll
        for (int ip = 0; ip < 20; ++ip)
            acc = FDOT2(fp[ip], wr[ip], acc);
        acc_out = fmaf(fmaxf(acc, 0.0f), W2v[j], acc_out);
    }
    return acc_out;
}

// =====================================================================
// sorted main: bf16 channel-last grids, spatially-ordered pts, no LDS
// =====================================================================
__global__ __launch_bounds__(256) void kp_main_sorted(
    const void* __restrict__ coords, const int* __restrict__ order,
    const u16* __restrict__ planes_s, const u16* __restrict__ vol_s,
    const u16* __restrict__ lines_s,
    const float* __restrict__ wbase,
    void* __restrict__ out, int M)
{
    int dt = detect_dt(coords);
    const half2* Wph  = (const half2*)wbase;
    const float* bv   = wbase + 1536;
    const half2* W1ph = (const half2*)(wbase + 1632);
    const float* b1v  = wbase + 4192;
    const float* W2v  = wbase + 4320;
    const float* b2v  = wbase + 4448;

    int p = blockIdx.x * 256 + threadIdx.x;
    p = min(p, M - 1);
    int sp = order[p];

    float x = gld(dt, coords, sp * 3 + 0);
    float y = gld(dt, coords, sp * 3 + 1);
    float z = gld(dt, coords, sp * 3 + 2);

    Samp sx = make_samp(x, 128), sy = make_samp(y, 128), sz = make_samp(z, 128);

    float feat[40];
#pragma unroll
    for (int o = 0; o < 40; ++o) feat[o] = 0.0f;

    // A: line_x & plane_yz(gx=y,gy=z) with Wx
    term_fused(lines_s + 0 * 4096, sx, planes_s + 1 * 524288, sy, sz, Wph + 0,    bv + 0,  feat);
    // B: line_y & plane_xz(gx=x,gy=z) with Wy
    term_fused(lines_s + 1 * 4096, sy, planes_s + 2 * 524288, sx, sz, Wph + 512,  bv + 32, feat);
    // C: line_z & plane_xy(gx=x,gy=y) with Wz
    term_fused(lines_s + 2 * 4096, sz, planes_s + 0 * 524288, sx, sy, Wph + 1024, bv + 64, feat);

    // volume
    {
        Samp vx = make_samp(x, 64), vy = make_samp(y, 64), vz = make_samp(z, 64);
#pragma unroll
        for (int corner = 0; corner < 8; ++corner) {
            int dx = corner & 1, dy = (corner >> 1) & 1, dz = corner >> 2;
            int xi = dx ? vx.i1 : vx.i0;
            int yi = dy ? vy.i1 : vy.i0;
            int zi = dz ? vz.i1 : vz.i0;
            float w = (dx ? vx.w1 : vx.w0) * (dy ? vy.w1 : vy.w0) * (dz ? vz.w1 : vz.w0);
            u16x8 v = *(const u16x8*)(vol_s + (((zi * 64) + yi) * 64 + xi) * 8);
#pragma unroll
            for (int c = 0; c < 8; ++c)
                feat[32 + c] = fmaf(w, bf2f(v[c]), feat[32 + c]);
        }
    }

    float r = head_mlp(feat, W1ph, b1v, W2v, b2v);
    if (dt) ((float*)out)[sp] = r;
    else    ((u16*)out)[sp] = f2bf(r);
}

// =====================================================================
// fallback path (ws too small): weights-only prep + direct gathers
// =====================================================================
__global__ void kp_prep_weights_fb(
    const void* __restrict__ coords,
    const void* __restrict__ Wx, const void* __restrict__ bx,
    const void* __restrict__ Wy, const void* __restrict__ by,
    const void* __restrict__ Wz, const void* __restrict__ bz,
    const void* __restrict__ W1, const void* __restrict__ b1,
    const void* __restrict__ W2, const void* __restrict__ b2,
    float* __restrict__ wbase)
{
    int dt = detect_dt(coords);
    int t = blockIdx.x * blockDim.x + threadIdx.x;
    weights_work(dt, t, Wx, bx, Wy, by, Wz, bz, W1, b1, W2, b2, wbase);
}

static __device__ __forceinline__ void term_direct(
    int dt, const void* __restrict__ L, const Samp& sl,
    const void* __restrict__ P, const Samp& sa, const Samp& sb,
    const half2* __restrict__ Wp, const float* __restrict__ b,
    float (&feat)[40])
{
    float ta[32], tb[32];
#pragma unroll
    for (int o = 0; o < 32; ++o) { ta[o] = b[o]; tb[o] = b[o]; }
    float w00 = sb.w0 * sa.w0, w01 = sb.w0 * sa.w1;
    float w10 = sb.w1 * sa.w0, w11 = sb.w1 * sa.w1;
    int i00 = sb.i0 * 128 + sa.i0, i01 = sb.i0 * 128 + sa.i1;
    int i10 = sb.i1 * 128 + sa.i0, i11 = sb.i1 * 128 + sa.i1;
#pragma unroll 1
    for (int kp = 0; kp < 16; ++kp) {
        int c0 = 2 * kp, c1 = 2 * kp + 1;
        float el0 = sl.w0 * gld(dt, L, c0 * 128 + sl.i0) + sl.w1 * gld(dt, L, c0 * 128 + sl.i1);
        float el1 = sl.w0 * gld(dt, L, c1 * 128 + sl.i0) + sl.w1 * gld(dt, L, c1 * 128 + sl.i1);
        float ep0 = w00 * gld(dt, P, c0 * 16384 + i00) + w01 * gld(dt, P, c0 * 16384 + i01)
                  + w10 * gld(dt, P, c0 * 16384 + i10) + w11 * gld(dt, P, c0 * 16384 + i11);
        float ep1 = w00 * gld(dt, P, c1 * 16384 + i00) + w01 * gld(dt, P, c1 * 16384 + i01)
                  + w10 * gld(dt, P, c1 * 16384 + i10) + w11 * gld(dt, P, c1 * 16384 + i11);
        half2 r1 = pk(fmaxf(el0, 0.0f), fmaxf(el1, 0.0f));
        half2 r2 = pk(fmaxf(ep0, 0.0f), fmaxf(ep1, 0.0f));
        const half2* wr = Wp + kp * 32;
#pragma unroll
        for (int o = 0; o < 32; ++o) {
            half2 w = wr[o];
            ta[o] = FDOT2(r1, w, ta[o]);
            tb[o] = FDOT2(r2, w, tb[o]);
        }
    }
#pragma unroll
    for (int o = 0; o < 32; ++o) feat[o] = fmaf(ta[o], tb[o], feat[o]);
}

__global__ __launch_bounds__(256) void kp_main_direct(
    const void* __restrict__ coords,
    const void* __restrict__ lx, const void* __restrict__ ly, const void* __restrict__ lz,
    const void* __restrict__ pxy, const void* __restrict__ pyz, const void* __restrict__ pxz,
    const void* __restrict__ vol,
    const float* __restrict__ wbase,
    void* __restrict__ out, int M)
{
    int dt = detect_dt(coords);
    const half2* Wph  = (const half2*)wbase;
    const float* bv   = wbase + 1536;
    const half2* W1ph = (const half2*)(wbase + 1632);
    const float* b1v  = wbase + 4192;
    const float* W2v  = wbase + 4320;
    const float* b2v  = wbase + 4448;

    int p = blockIdx.x * 256 + threadIdx.x;
    p = min(p, M - 1);

    float x = gld(dt, coords, p * 3 + 0);
    float y = gld(dt, coords, p * 3 + 1);
    float z = gld(dt, coords, p * 3 + 2);

    Samp sx = make_samp(x, 128), sy = make_samp(y, 128), sz = make_samp(z, 128);

    float feat[40];
#pragma unroll
    for (int o = 0; o < 40; ++o) feat[o] = 0.0f;

    term_direct(dt, lx, sx, pyz, sy, sz, Wph + 0,    bv + 0,  feat);
    term_direct(dt, ly, sy, pxz, sx, sz, Wph + 512,  bv + 32, feat);
    term_direct(dt, lz, sz, pxy, sx, sy, Wph + 1024, bv + 64, feat);

    Samp vx = make_samp(x, 64), vy = make_samp(y, 64), vz = make_samp(z, 64);
#pragma unroll 1
    for (int corner = 0; corner < 8; ++corner) {
        int dx = corner & 1, dy = (corner >> 1) & 1, dz = corner >> 2;
        int xi = dx ? vx.i1 : vx.i0;
        int yi = dy ? vy.i1 : vy.i0;
        int zi = dz ? vz.i1 : vz.i0;
        float w = (dx ? vx.w1 : vx.w0) * (dy ? vy.w1 : vy.w0) * (dz ? vz.w1 : vz.w0);
        int pos = ((zi * 64) + yi) * 64 + xi;
#pragma unroll
        for (int c = 0; c < 8; ++c)
            feat[32 + c] = fmaf(w, gld(dt, vol, c * 262144 + pos), feat[32 + c]);
    }

    float r = head_mlp(feat, W1ph, b1v, W2v, b2v);
    if (dt) ((float*)out)[p] = r;
    else    ((u16*)out)[p] = f2bf(r);
}

// =====================================================================
extern "C" void kernel_launch(void* const* d_in, const int* in_sizes, int n_in,
                              void* d_out, int out_size, void* d_ws, size_t ws_size,
                              hipStream_t stream) {
    const void* coords = d_in[0];
    const void* lx  = d_in[1];
    const void* ly  = d_in[2];
    const void* lz  = d_in[3];
    const void* pxy = d_in[4];
    const void* pyz = d_in[5];
    const void* pxz = d_in[6];
    const void* vol = d_in[7];
    const void* Wx  = d_in[8];
    const void* bx  = d_in[9];
    const void* Wy  = d_in[10];
    const void* by  = d_in[11];
    const void* Wz  = d_in[12];
    const void* bz  = d_in[13];
    const void* W1  = d_in[14];
    const void* b1  = d_in[15];
    const void* W2  = d_in[16];
    const void* b2  = d_in[17];

    int M = in_sizes[0] / 3;

    char* ws = (char*)d_ws;
    float*        wbase    = (float*)(ws + WF_OFF);
    u16*          planes_s = (u16*)(ws + PLANES_S_OFF);
    u16*          vol_s    = (u16*)(ws + VOL_S_OFF);
    u16*          lines_s  = (u16*)(ws + LINES_S_OFF);
    unsigned int* part     = (unsigned int*)(ws + PART_OFF);
    unsigned int* offs     = (unsigned int*)(ws + OFFS_OFF);
    int*          order    = (int*)(ws + ORDER_OFF);

    size_t need_sorted = (size_t)ORDER_OFF + (size_t)M * 4u;

    int blocks = (M + 255) / 256;
    if (ws_size >= need_sorted) {
        kp_prep_all<<<1848, 256, 0, stream>>>(coords, lx, ly, lz, pxy, pyz, pxz, vol,
                                              Wx, bx, Wy, by, Wz, bz, W1, b1, W2, b2,
                                              wbase, planes_s, vol_s, lines_s, part, M);
        kp_scan<<<1, 256, 0, stream>>>(part, offs);
        kp_scatter<<<480, 256, 0, stream>>>(coords, offs, order, M);
        kp_main_sorted<<<blocks, 256, 0, stream>>>(coords, order, planes_s, vol_s,
                                                   lines_s, wbase, d_out, M);
    } else {
        kp_prep_weights_fb<<<18, 256, 0, stream>>>(coords, Wx, bx, Wy, by, Wz, bz,
                                                   W1, b1, W2, b2, wbase);
        kp_main_direct<<<blocks, 256, 0, stream>>>(coords, lx, ly, lz, pxy, pyz, pxz,
                                                   vol, wbase, d_out, M);
    }
}

// Round 8
// 292.024 us; speedup vs baseline: 1.0967x; 1.0967x over previous
//
#include <hip/hip_runtime.h>

typedef unsigned short u16;
typedef u16 u16x8 __attribute__((ext_vector_type(8)));
typedef _Float16 half2 __attribute__((ext_vector_type(2)));
typedef _Float16 h8v __attribute__((ext_vector_type(8)));
typedef float f4v __attribute__((ext_vector_type(4)));

union H8 { h8v v; half2 p[4]; };

// ---------- bf16 helpers ----------
static __device__ __forceinline__ float bf2f(u16 u) {
    union { unsigned int i; float f; } v;
    v.i = ((unsigned int)u) << 16;
    return v.f;
}
static __device__ __forceinline__ u16 f2bf(float f) {
    union { float f; unsigned int i; } v;
    v.f = f;
    unsigned int x = v.i;
    x += 0x7fffu + ((x >> 16) & 1u);   // RNE
    return (u16)(x >> 16);
}
static __device__ __forceinline__ float gld(int dt, const void* p, int i) {
    return dt ? ((const float*)p)[i] : bf2f(((const u16*)p)[i]);
}
static __device__ __forceinline__ int detect_dt(const void* coords) {
    u16 v = ((const u16*)coords)[threadIdx.x & 63];
    int e = (v >> 7) & 0xFF;
    bool inr = (e >= 90) && (e <= 126);
    unsigned long long m = __ballot(inr);
    return (__popcll(m) >= 56) ? 0 : 1;   // 0=bf16, 1=f32
}
static __device__ __forceinline__ half2 pk(float a, float b) {
    return __builtin_bit_cast(half2, __builtin_amdgcn_cvt_pkrtz(a, b));
}

// ---------- ws layout (bytes) ----------
#define WF_OFF        64u
#define PLANES_S_OFF  34304u         // 3*524288 u16
#define VOL_S_OFF     3180032u       // 2097152 u16
#define LINES_S_OFF   7374336u       // 12288 u16
#define PART_OFF      7398912u       // 32*4096 u32
#define ORDER_OFF     7939584u       // 4*M

#define NBUCK 4096
#define HBLOCKS 32

// weight region (float units from wbase):
//   Wt  f16[3][32 o][32 c]   : halves [0,3072)      = floats [0,1536)
//   bv  f32[96]              : floats [1536,1632)
//   W1t f16[128 j][64 i pad] : halves [0,8192) at (wbase+1632)
//   b1v f32[128]             : floats [5728,5856)
//   W2v f32[128]             : floats [5856,5984)
//   b2v f32[1]               : float  [5984]

// =====================================================================
// spatial key
// =====================================================================
static __device__ __forceinline__ int make_key(int dt, const void* coords, int p) {
    float x = gld(dt, coords, p * 3 + 0);
    float y = gld(dt, coords, p * 3 + 1);
    float z = gld(dt, coords, p * 3 + 2);
    int kx = min(max((int)((x + 1.0f) * 8.0f), 0), 15);
    int ky = min(max((int)((y + 1.0f) * 8.0f), 0), 15);
    int kz = min(max((int)((z + 1.0f) * 8.0f), 0), 15);
    return (kz * 16 + ky) * 16 + kx;
}

// =====================================================================
// weight packing (f16 MFMA layouts)
// =====================================================================
static __device__ __forceinline__ void weights_work(
    int dt, int r,
    const void* Wx, const void* bx, const void* Wy, const void* by,
    const void* Wz, const void* bz, const void* W1, const void* b1,
    const void* W2, const void* b2, float* wbase)
{
    _Float16* WtH = (_Float16*)wbase;
    float*    bv  = wbase + 1536;
    _Float16* W1H = (_Float16*)(wbase + 1632);
    float*    b1v = wbase + 5728;
    float*    W2v = wbase + 5856;
    float*    b2v = wbase + 5984;
    if (r < 3072) {
        int m = r >> 10, idx = r & 1023;
        int o = idx >> 5, c = idx & 31;
        const void* s = (m == 0) ? Wx : (m == 1) ? Wy : Wz;
        WtH[r] = (_Float16)gld(dt, s, c * 32 + o);   // Wt[m][o][c] = W[c][o]
    } else if (r < 3168) {
        int q2 = r - 3072;
        int m = q2 >> 5, c = q2 & 31;
        const void* s = (m == 0) ? bx : (m == 1) ? by : bz;
        bv[q2] = gld(dt, s, c);
    } else if (r < 11360) {
        int idx = r - 3168;                 // j*64 + i
        int j = idx >> 6, i = idx & 63;
        W1H[idx] = (i < 40) ? (_Float16)gld(dt, W1, i * 128 + j) : (_Float16)0.0f;
    } else if (r < 11488) {
        b1v[r - 11360] = gld(dt, b1, r - 11360);
    } else if (r < 11616) {
        W2v[r - 11488] = gld(dt, W2, r - 11488);
    } else if (r == 11616) {
        b2v[0] = gld(dt, b2, 0);
    }
}

// =====================================================================
// fused prep: grid transpose (0..1797) + weights (1798..1843)
//           + histogram partials, plain stores (1844..1875)
// =====================================================================
__global__ __launch_bounds__(256) void kp_prep_all(
    const void* __restrict__ coords,
    const void* __restrict__ lx, const void* __restrict__ ly,
    const void* __restrict__ lz,
    const void* __restrict__ pxy, const void* __restrict__ pyz,
    const void* __restrict__ pxz, const void* __restrict__ vol,
    const void* __restrict__ Wx, const void* __restrict__ bx,
    const void* __restrict__ Wy, const void* __restrict__ by,
    const void* __restrict__ Wz, const void* __restrict__ bz,
    const void* __restrict__ W1, const void* __restrict__ b1,
    const void* __restrict__ W2, const void* __restrict__ b2,
    float* __restrict__ wbase,
    u16* __restrict__ planes_s, u16* __restrict__ vol_s,
    u16* __restrict__ lines_s, unsigned int* __restrict__ part, int M)
{
    __shared__ unsigned int lh[NBUCK];
    int dt = detect_dt(coords);
    int blk = blockIdx.x;
    if (blk < 1798) {
        int t = blk * 256 + threadIdx.x;   // [0, 460288)
        u16x8 v;
        if (t < 196608) {                 // planes: 8 consecutive out u16
            int o = t * 8;
            int pl = o >> 19;
            int r  = o & 524287;
            int pos = r >> 5, c0 = r & 31;
            const void* src = (pl == 0) ? pxy : (pl == 1) ? pyz : pxz;
#pragma unroll
            for (int i = 0; i < 8; ++i)
                v[i] = dt ? f2bf(((const float*)src)[(c0 + i) * 16384 + pos])
                          : ((const u16*)src)[(c0 + i) * 16384 + pos];
            *(u16x8*)(planes_s + o) = v;
        } else if (t < 458752) {          // volume: thread = one pos, 8 channels
            int pos = t - 196608;
#pragma unroll
            for (int c = 0; c < 8; ++c)
                v[c] = dt ? f2bf(((const float*)vol)[c * 262144 + pos])
                          : ((const u16*)vol)[c * 262144 + pos];
            *(u16x8*)(vol_s + pos * 8) = v;
        } else {                          // lines
            int o = (t - 458752) * 8;
            int l = o >> 12, rr = o & 4095;
            int pos = rr >> 5, c0 = rr & 31;
            const void* src = (l == 0) ? lx : (l == 1) ? ly : lz;
#pragma unroll
            for (int i = 0; i < 8; ++i)
                v[i] = dt ? f2bf(((const float*)src)[(c0 + i) * 128 + pos])
                          : ((const u16*)src)[(c0 + i) * 128 + pos];
            *(u16x8*)(lines_s + o) = v;
        }
    } else if (blk < 1844) {
        int r = (blk - 1798) * 256 + threadIdx.x;   // [0, 11776)
        weights_work(dt, r, Wx, bx, Wy, by, Wz, bz, W1, b1, W2, b2, wbase);
    } else {
        int b = blk - 1844;               // [0, 32)
        for (int i = threadIdx.x; i < NBUCK; i += 256) lh[i] = 0u;
        __syncthreads();
        for (int p = b * 256 + threadIdx.x; p < M; p += HBLOCKS * 256)
            atomicAdd(&lh[make_key(dt, coords, p)], 1u);
        __syncthreads();
        for (int i = threadIdx.x; i < NBUCK; i += 256)
            part[b * NBUCK + i] = lh[i];
    }
}

// =====================================================================
// deterministic scatter: 32 blocks, local scan + LDS counters,
// NO global atomics. Block b must walk the same range as hist block b.
// =====================================================================
__global__ __launch_bounds__(256) void kp_scatter_det(
    const void* __restrict__ coords, const unsigned int* __restrict__ part,
    int* __restrict__ order, int M)
{
    __shared__ unsigned int cnt[NBUCK];
    __shared__ unsigned int psum[256];
    int b = blockIdx.x;          // [0, 32)
    int t = threadIdx.x;
    unsigned int bs_tot[16], bs_bef[16];
    unsigned int s = 0;
#pragma unroll
    for (int i = 0; i < 16; ++i) {
        int bkt = t * 16 + i;
        unsigned int tot = 0, bef = 0;
#pragma unroll
        for (int k = 0; k < HBLOCKS; ++k) {
            unsigned int v = part[k * NBUCK + bkt];
            tot += v;
            if (k < b) bef += v;
        }
        bs_tot[i] = tot; bs_bef[i] = bef; s += tot;
    }
    psum[t] = s;
    __syncthreads();
    if (t == 0) {
        unsigned int run = 0;
        for (int i = 0; i < 256; ++i) { unsigned int v = psum[i]; psum[i] = run; run += v; }
    }
    __syncthreads();
    unsigned int run = psum[t];
#pragma unroll
    for (int i = 0; i < 16; ++i) {
        cnt[t * 16 + i] = run + bs_bef[i];
        run += bs_tot[i];
    }
    __syncthreads();
    int dt = detect_dt(coords);
    for (int p = b * 256 + t; p < M; p += HBLOCKS * 256) {
        int key = make_key(dt, coords, p);
        unsigned int pos = atomicAdd(&cnt[key], 1u);
        order[pos] = p;
    }
}

// =====================================================================
// shared math
// =====================================================================
struct Samp { int i0, i1; float w0, w1; };

static __device__ __forceinline__ Samp make_samp(float g, int N) {
    float ix = (g + 1.0f) * 0.5f * (float)(N - 1);
    float fl = floorf(ix);
    float w  = ix - fl;
    int i  = (int)fl;
    int i1 = i + 1;
    float v0 = (i  >= 0 && i  < N) ? 1.0f : 0.0f;
    float v1 = (i1 >= 0 && i1 < N) ? 1.0f : 0.0f;
    Samp s;
    s.w0 = (1.0f - w) * v0;
    s.w1 = w * v1;
    s.i0 = min(max(i, 0), N - 1);
    s.i1 = min(max(i1, 0), N - 1);
    return s;
}

#define MFMA16(a, b, c) __builtin_amdgcn_mfma_f32_16x16x32_f16((a), (b), (c), 0, 0, 0)

// E row stride 40 halves (80 B: 16B-aligned rows, ~2-way banks)
#define SRE 40
// E2 row stride 72 halves (144 B: 16B-aligned)
#define SR2 72

// one product term: interp -> LDS E (f16, relu'd) -> MFMA ta,tb -> feat += ta*tb
static __device__ __forceinline__ void term_mfma(
    int lane, const u16* __restrict__ Ls, const Samp& sl,
    const u16* __restrict__ Ps, const Samp& sa, const Samp& sb,
    const _Float16* __restrict__ Wt, const float* __restrict__ bvt,
    _Float16* El, _Float16* Ep, float (&feat)[4][2][4])
{
    int q = lane >> 4, l15 = lane & 15;
    const u16x8* l0  = (const u16x8*)(Ls + sl.i0 * 32);
    const u16x8* l1  = (const u16x8*)(Ls + sl.i1 * 32);
    const u16x8* p00 = (const u16x8*)(Ps + (sb.i0 * 128 + sa.i0) * 32);
    const u16x8* p01 = (const u16x8*)(Ps + (sb.i0 * 128 + sa.i1) * 32);
    const u16x8* p10 = (const u16x8*)(Ps + (sb.i1 * 128 + sa.i0) * 32);
    const u16x8* p11 = (const u16x8*)(Ps + (sb.i1 * 128 + sa.i1) * 32);
    float w00 = sb.w0 * sa.w0, w01 = sb.w0 * sa.w1;
    float w10 = sb.w1 * sa.w0, w11 = sb.w1 * sa.w1;
#pragma unroll
    for (int cc = 0; cc < 4; ++cc) {
        u16x8 A0 = l0[cc], A1 = l1[cc];
        u16x8 Q00 = p00[cc], Q01 = p01[cc], Q10 = p10[cc], Q11 = p11[cc];
        H8 hl, hp;
#pragma unroll
        for (int kk = 0; kk < 4; ++kk) {
            int k0 = 2 * kk, k1 = k0 + 1;
            float el0 = sl.w0 * bf2f(A0[k0]) + sl.w1 * bf2f(A1[k0]);
            float el1 = sl.w0 * bf2f(A0[k1]) + sl.w1 * bf2f(A1[k1]);
            float ep0 = w00 * bf2f(Q00[k0]) + w01 * bf2f(Q01[k0])
                      + w10 * bf2f(Q10[k0]) + w11 * bf2f(Q11[k0]);
            float ep1 = w00 * bf2f(Q00[k1]) + w01 * bf2f(Q01[k1])
                      + w10 * bf2f(Q10[k1]) + w11 * bf2f(Q11[k1]);
            hl.p[kk] = pk(fmaxf(el0, 0.0f), fmaxf(el1, 0.0f));
            hp.p[kk] = pk(fmaxf(ep0, 0.0f), fmaxf(ep1, 0.0f));
        }
        *(h8v*)&El[lane * SRE + cc * 8] = hl.v;
        *(h8v*)&Ep[lane * SRE + cc * 8] = hp.v;
    }
    __syncthreads();
    // B-frags (from global, L1/L2-hot): B[k][n]: n=l15, k=q*8+j
    h8v bf0 = *(const h8v*)&Wt[(l15) * 32 + q * 8];
    h8v bf1 = *(const h8v*)&Wt[(16 + l15) * 32 + q * 8];
    float bb0 = bvt[l15], bb1 = bvt[16 + l15];
    f4v c0 = {bb0, bb0, bb0, bb0};
    f4v c1 = {bb1, bb1, bb1, bb1};
#pragma unroll
    for (int mt = 0; mt < 4; ++mt) {
        h8v aL = *(const h8v*)&El[(mt * 16 + l15) * SRE + q * 8];
        h8v aP = *(const h8v*)&Ep[(mt * 16 + l15) * SRE + q * 8];
        f4v ta0 = MFMA16(aL, bf0, c0);
        f4v tb0 = MFMA16(aP, bf0, c0);
        f4v ta1 = MFMA16(aL, bf1, c1);
        f4v tb1 = MFMA16(aP, bf1, c1);
#pragma unroll
        for (int r = 0; r < 4; ++r) {
            feat[mt][0][r] += ta0[r] * tb0[r];
            feat[mt][1][r] += ta1[r] * tb1[r];
        }
    }
    __syncthreads();
}

// =====================================================================
// MFMA main
// =====================================================================
__global__ __launch_bounds__(256) void kp_main_mfma(
    const void* __restrict__ coords, const int* __restrict__ order,
    const u16* __restrict__ planes_s, const u16* __restrict__ vol_s,
    const u16* __restrict__ lines_s,
    const float* __restrict__ wbase,
    void* __restrict__ out, int M)
{
    __shared__ _Float16 eb[4][5120];   // per-wave: El[64*40] | Ep[64*40]; reused as E2[64*72]
    __shared__ float res[4][64];
    int dt = detect_dt(coords);
    const _Float16* WtH = (const _Float16*)wbase;
    const float*    bv  = wbase + 1536;
    const _Float16* W1H = (const _Float16*)(wbase + 1632);
    const float*    b1v = wbase + 5728;
    const float*    W2v = wbase + 5856;
    const float*    b2v = wbase + 5984;

    int tid = threadIdx.x;
    int wid = tid >> 6, lane = tid & 63;
    int q = lane >> 4, l15 = lane & 15;
    _Float16* El = eb[wid];
    _Float16* Ep = eb[wid] + 2560;
    _Float16* E2 = eb[wid];

    int p = blockIdx.x * 256 + tid;
    p = min(p, M - 1);
    int sp = order[p];

    float x = gld(dt, coords, sp * 3 + 0);
    float y = gld(dt, coords, sp * 3 + 1);
    float z = gld(dt, coords, sp * 3 + 2);

    Samp sx = make_samp(x, 128), sy = make_samp(y, 128), sz = make_samp(z, 128);

    float feat[4][2][4];
#pragma unroll
    for (int mt = 0; mt < 4; ++mt)
#pragma unroll
        for (int n = 0; n < 2; ++n)
#pragma unroll
            for (int r = 0; r < 4; ++r) feat[mt][n][r] = 0.0f;

    // A: line_x & plane_yz(gx=y,gy=z) with Wx
    term_mfma(lane, lines_s + 0 * 4096, sx, planes_s + 1 * 524288, sy, sz,
              WtH + 0,    bv + 0,  El, Ep, feat);
    // B: line_y & plane_xz(gx=x,gy=z) with Wy
    term_mfma(lane, lines_s + 1 * 4096, sy, planes_s + 2 * 524288, sx, sz,
              WtH + 1024, bv + 32, El, Ep, feat);
    // C: line_z & plane_xy(gx=x,gy=y) with Wz
    term_mfma(lane, lines_s + 2 * 4096, sz, planes_s + 0 * 524288, sx, sy,
              WtH + 2048, bv + 64, El, Ep, feat);

    // ---- stage feat (D layout) + vol + zero-pad into E2[pt][64] ----
#pragma unroll
    for (int mt = 0; mt < 4; ++mt)
#pragma unroll
        for (int n = 0; n < 2; ++n)
#pragma unroll
            for (int r = 0; r < 4; ++r)
                E2[(mt * 16 + q * 4 + r) * SR2 + n * 16 + l15] =
                    (_Float16)feat[mt][n][r];
    {
        // volume trilinear -> E2[own pt][32..39]
        Samp vx = make_samp(x, 64), vy = make_samp(y, 64), vz = make_samp(z, 64);
        float vf[8];
#pragma unroll
        for (int c = 0; c < 8; ++c) vf[c] = 0.0f;
#pragma unroll
        for (int corner = 0; corner < 8; ++corner) {
            int dx = corner & 1, dy = (corner >> 1) & 1, dz = corner >> 2;
            int xi = dx ? vx.i1 : vx.i0;
            int yi = dy ? vy.i1 : vy.i0;
            int zi = dz ? vz.i1 : vz.i0;
            float w = (dx ? vx.w1 : vx.w0) * (dy ? vy.w1 : vy.w0) * (dz ? vz.w1 : vz.w0);
            u16x8 v = *(const u16x8*)(vol_s + (((zi * 64) + yi) * 64 + xi) * 8);
#pragma unroll
            for (int c = 0; c < 8; ++c)
                vf[c] = fmaf(w, bf2f(v[c]), vf[c]);
        }
        H8 hv;
#pragma unroll
        for (int k = 0; k < 4; ++k) hv.p[k] = pk(vf[2 * k], vf[2 * k + 1]);
        *(h8v*)&E2[lane * SR2 + 32] = hv.v;
        h8v zz = {};
        *(h8v*)&E2[lane * SR2 + 40] = zz;
        *(h8v*)&E2[lane * SR2 + 48] = zz;
        *(h8v*)&E2[lane * SR2 + 56] = zz;
    }
    __syncthreads();

    // ---- head: hidden = relu(feat @ W1 + b1); out = hidden @ W2 + b2 ----
    h8v af[4][2];
#pragma unroll
    for (int mt = 0; mt < 4; ++mt)
#pragma unroll
        for (int ks = 0; ks < 2; ++ks)
            af[mt][ks] = *(const h8v*)&E2[(mt * 16 + l15) * SR2 + ks * 32 + q * 8];

    float s[4][4];
#pragma unroll
    for (int mt = 0; mt < 4; ++mt)
#pragma unroll
        for (int r = 0; r < 4; ++r) s[mt][r] = 0.0f;

#pragma unroll
    for (int NT = 0; NT < 8; ++NT) {
        int o = NT * 16 + l15;
        h8v b0 = *(const h8v*)&W1H[o * 64 + q * 8];
        h8v b1f = *(const h8v*)&W1H[o * 64 + 32 + q * 8];
        float w2 = W2v[o];
        float bb = b1v[o];
        f4v cinit = {bb, bb, bb, bb};
#pragma unroll
        for (int mt = 0; mt < 4; ++mt) {
            f4v c = MFMA16(af[mt][0], b0, cinit);
            c = MFMA16(af[mt][1], b1f, c);
#pragma unroll
            for (int r = 0; r < 4; ++r)
                s[mt][r] = fmaf(fmaxf(c[r], 0.0f), w2, s[mt][r]);
        }
    }
    // reduce over the 16 lanes of each quad (butterfly)
#pragma unroll
    for (int mt = 0; mt < 4; ++mt)
#pragma unroll
        for (int r = 0; r < 4; ++r) {
            float v = s[mt][r];
            v += __shfl_xor(v, 1);
            v += __shfl_xor(v, 2);
            v += __shfl_xor(v, 4);
            v += __shfl_xor(v, 8);
            s[mt][r] = v;
        }
    if (l15 == 0) {
#pragma unroll
        for (int mt = 0; mt < 4; ++mt)
#pragma unroll
            for (int r = 0; r < 4; ++r)
                res[wid][mt * 16 + q * 4 + r] = s[mt][r];
    }
    __syncthreads();
    float rr = res[wid][lane] + b2v[0];
    if (dt) ((float*)out)[sp] = rr;
    else    ((u16*)out)[sp] = f2bf(rr);
}

// =====================================================================
// fallback path (ws too small): weights-only prep + direct gathers
// =====================================================================
__global__ void kp_prep_weights_fb(
    const void* __restrict__ coords,
    const void* __restrict__ Wx, const void* __restrict__ bx,
    const void* __restrict__ Wy, const void* __restrict__ by,
    const void* __restrict__ Wz, const void* __restrict__ bz,
    const void* __restrict__ W1, const void* __restrict__ b1,
    const void* __restrict__ W2, const void* __restrict__ b2,
    float* __restrict__ wbase)
{
    int dt = detect_dt(coords);
    int t = blockIdx.x * blockDim.x + threadIdx.x;
    weights_work(dt, t, Wx, bx, Wy, by, Wz, bz, W1, b1, W2, b2, wbase);
}

__global__ __launch_bounds__(256) void kp_main_direct(
    const void* __restrict__ coords,
    const void* __restrict__ lx, const void* __restrict__ ly, const void* __restrict__ lz,
    const void* __restrict__ pxy, const void* __restrict__ pyz, const void* __restrict__ pxz,
    const void* __restrict__ vol,
    const float* __restrict__ wbase,
    void* __restrict__ out, int M)
{
    int dt = detect_dt(coords);
    const _Float16* WtH = (const _Float16*)wbase;
    const float*    bv  = wbase + 1536;
    const _Float16* W1H = (const _Float16*)(wbase + 1632);
    const float*    b1v = wbase + 5728;
    const float*    W2v = wbase + 5856;
    const float*    b2v = wbase + 5984;

    int p = blockIdx.x * 256 + threadIdx.x;
    p = min(p, M - 1);

    float x = gld(dt, coords, p * 3 + 0);
    float y = gld(dt, coords, p * 3 + 1);
    float z = gld(dt, coords, p * 3 + 2);

    Samp sx = make_samp(x, 128), sy = make_samp(y, 128), sz = make_samp(z, 128);

    float feat[40];
#pragma unroll
    for (int o = 0; o < 40; ++o) feat[o] = 0.0f;

    const void* Ls[3] = {lx, ly, lz};
    const void* Psv[3] = {pyz, pxz, pxy};
    Samp sl3[3] = {sx, sy, sz};
    Samp sa3[3] = {sy, sx, sx};
    Samp sb3[3] = {sz, sz, sy};
#pragma unroll 1
    for (int m = 0; m < 3; ++m) {
        float ta[32], tb[32];
        const float* bvt = bv + m * 32;
        const _Float16* Wt = WtH + m * 1024;
#pragma unroll
        for (int o = 0; o < 32; ++o) { ta[o] = bvt[o]; tb[o] = bvt[o]; }
        Samp sl = sl3[m], sa = sa3[m], sb = sb3[m];
        float w00 = sb.w0 * sa.w0, w01 = sb.w0 * sa.w1;
        float w10 = sb.w1 * sa.w0, w11 = sb.w1 * sa.w1;
        int i00 = sb.i0 * 128 + sa.i0, i01 = sb.i0 * 128 + sa.i1;
        int i10 = sb.i1 * 128 + sa.i0, i11 = sb.i1 * 128 + sa.i1;
#pragma unroll 1
        for (int c = 0; c < 32; ++c) {
            float el = sl.w0 * gld(dt, Ls[m], c * 128 + sl.i0)
                     + sl.w1 * gld(dt, Ls[m], c * 128 + sl.i1);
            float ep = w00 * gld(dt, Psv[m], c * 16384 + i00)
                     + w01 * gld(dt, Psv[m], c * 16384 + i01)
                     + w10 * gld(dt, Psv[m], c * 16384 + i10)
                     + w11 * gld(dt, Psv[m], c * 16384 + i11);
            float r1 = fmaxf(el, 0.0f), r2 = fmaxf(ep, 0.0f);
#pragma unroll
            for (int o = 0; o < 32; ++o) {
                float w = (float)Wt[o * 32 + c];
                ta[o] = fmaf(r1, w, ta[o]);
                tb[o] = fmaf(r2, w, tb[o]);
            }
        }
#pragma unroll
        for (int o = 0; o < 32; ++o) feat[o] = fmaf(ta[o], tb[o], feat[o]);
    }

    Samp vx = make_samp(x, 64), vy = make_samp(y, 64), vz = make_samp(z, 64);
#pragma unroll 1
    for (int corner = 0; corner < 8; ++corner) {
        int dx = corner & 1, dy = (corner >> 1) & 1, dz = corner >> 2;
        int xi = dx ? vx.i1 : vx.i0;
        int yi = dy ? vy.i1 : vy.i0;
        int zi = dz ? vz.i1 : vz.i0;
        float w = (dx ? vx.w1 : vx.w0) * (dy ? vy.w1 : vy.w0) * (dz ? vz.w1 : vz.w0);
        int pos = ((zi * 64) + yi) * 64 + xi;
#pragma unroll
        for (int c = 0; c < 8; ++c)
            feat[32 + c] = fmaf(w, gld(dt, vol, c * 262144 + pos), feat[32 + c]);
    }

    float acc_out = b2v[0];
#pragma unroll 2
    for (int j = 0; j < 128; ++j) {
        float acc = b1v[j];
        const _Float16* wr = W1H + j * 64;
#pragma unroll
        for (int i = 0; i < 40; ++i)
            acc = fmaf(feat[i], (float)wr[i], acc);
        acc_out = fmaf(fmaxf(acc, 0.0f), W2v[j], acc_out);
    }
    if (dt) ((float*)out)[p] = acc_out;
    else    ((u16*)out)[p] = f2bf(acc_out);
}

// =====================================================================
extern "C" void kernel_launch(void* const* d_in, const int* in_sizes, int n_in,
                              void* d_out, int out_size, void* d_ws, size_t ws_size,
                              hipStream_t stream) {
    const void* coords = d_in[0];
    const void* lx  = d_in[1];
    const void* ly  = d_in[2];
    const void* lz  = d_in[3];
    const void* pxy = d_in[4];
    const void* pyz = d_in[5];
    const void* pxz = d_in[6];
    const void* vol = d_in[7];
    const void* Wx  = d_in[8];
    const void* bx  = d_in[9];
    const void* Wy  = d_in[10];
    const void* by  = d_in[11];
    const void* Wz  = d_in[12];
    const void* bz  = d_in[13];
    const void* W1  = d_in[14];
    const void* b1  = d_in[15];
    const void* W2  = d_in[16];
    const void* b2  = d_in[17];

    int M = in_sizes[0] / 3;

    char* ws = (char*)d_ws;
    float*        wbase    = (float*)(ws + WF_OFF);
    u16*          planes_s = (u16*)(ws + PLANES_S_OFF);
    u16*          vol_s    = (u16*)(ws + VOL_S_OFF);
    u16*          lines_s  = (u16*)(ws + LINES_S_OFF);
    unsigned int* part     = (unsigned int*)(ws + PART_OFF);
    int*          order    = (int*)(ws + ORDER_OFF);

    size_t need_sorted = (size_t)ORDER_OFF + (size_t)M * 4u;

    int blocks = (M + 255) / 256;
    if (ws_size >= need_sorted) {
        kp_prep_all<<<1876, 256, 0, stream>>>(coords, lx, ly, lz, pxy, pyz, pxz, vol,
                                              Wx, bx, Wy, by, Wz, bz, W1, b1, W2, b2,
                                              wbase, planes_s, vol_s, lines_s, part, M);
        kp_scatter_det<<<HBLOCKS, 256, 0, stream>>>(coords, part, order, M);
        kp_main_mfma<<<blocks, 256, 0, stream>>>(coords, order, planes_s, vol_s,
                                                 lines_s, wbase, d_out, M);
    } else {
        kp_prep_weights_fb<<<46, 256, 0, stream>>>(coords, Wx, bx, Wy, by, Wz, bz,
                                                   W1, b1, W2, b2, wbase);
        kp_main_direct<<<blocks, 256, 0, stream>>>(coords, lx, ly, lz, pxy, pyz, pxz,
                                                   vol, wbase, d_out, M);
    }
}

// Round 9
// 218.898 us; speedup vs baseline: 1.4631x; 1.3341x over previous
//
#include <hip/hip_runtime.h>

typedef unsigned short u16;
typedef u16 u16x8 __attribute__((ext_vector_type(8)));
typedef _Float16 half2 __attribute__((ext_vector_type(2)));
typedef _Float16 h8v __attribute__((ext_vector_type(8)));
typedef float f4v __attribute__((ext_vector_type(4)));

union H8 { h8v v; half2 p[4]; };

// ---------- bf16 helpers ----------
static __device__ __forceinline__ float bf2f(u16 u) {
    union { unsigned int i; float f; } v;
    v.i = ((unsigned int)u) << 16;
    return v.f;
}
static __device__ __forceinline__ u16 f2bf(float f) {
    union { float f; unsigned int i; } v;
    v.f = f;
    unsigned int x = v.i;
    x += 0x7fffu + ((x >> 16) & 1u);   // RNE
    return (u16)(x >> 16);
}
static __device__ __forceinline__ float gld(int dt, const void* p, int i) {
    return dt ? ((const float*)p)[i] : bf2f(((const u16*)p)[i]);
}
static __device__ __forceinline__ int detect_dt(const void* coords) {
    u16 v = ((const u16*)coords)[threadIdx.x & 63];
    int e = (v >> 7) & 0xFF;
    bool inr = (e >= 90) && (e <= 126);
    unsigned long long m = __ballot(inr);
    return (__popcll(m) >= 56) ? 0 : 1;   // 0=bf16, 1=f32
}
static __device__ __forceinline__ half2 pk(float a, float b) {
    return __builtin_bit_cast(half2, __builtin_amdgcn_cvt_pkrtz(a, b));
}

// ---------- ws layout (bytes) ----------
#define WF_OFF        64u
#define PLANES_S_OFF  34304u         // 3*524288 u16
#define VOL_S_OFF     3180032u       // 2097152 u16
#define LINES_S_OFF   7374336u       // 12288 u16
#define PART_OFF      7398912u       // 256*4096 u32 = 4 MB
#define TOT_OFF       11593216u      // 4096 u32
#define ORDER_OFF     11609600u      // 4*M

#define NBUCK 4096
#define HBLOCKS 256

// weight region (float units from wbase):
//   Wt  f16[3][32 o][32 c]   | bv f32[96] | W1t f16[128][64 pad]
//   b1v f32[128] | W2v f32[128] | b2v f32[1]

// =====================================================================
// spatial key
// =====================================================================
static __device__ __forceinline__ int make_key(int dt, const void* coords, int p) {
    float x = gld(dt, coords, p * 3 + 0);
    float y = gld(dt, coords, p * 3 + 1);
    float z = gld(dt, coords, p * 3 + 2);
    int kx = min(max((int)((x + 1.0f) * 8.0f), 0), 15);
    int ky = min(max((int)((y + 1.0f) * 8.0f), 0), 15);
    int kz = min(max((int)((z + 1.0f) * 8.0f), 0), 15);
    return (kz * 16 + ky) * 16 + kx;
}

// =====================================================================
// weight packing (f16 MFMA layouts)
// =====================================================================
static __device__ __forceinline__ void weights_work(
    int dt, int r,
    const void* Wx, const void* bx, const void* Wy, const void* by,
    const void* Wz, const void* bz, const void* W1, const void* b1,
    const void* W2, const void* b2, float* wbase)
{
    _Float16* WtH = (_Float16*)wbase;
    float*    bv  = wbase + 1536;
    _Float16* W1H = (_Float16*)(wbase + 1632);
    float*    b1v = wbase + 5728;
    float*    W2v = wbase + 5856;
    float*    b2v = wbase + 5984;
    if (r < 3072) {
        int m = r >> 10, idx = r & 1023;
        int o = idx >> 5, c = idx & 31;
        const void* s = (m == 0) ? Wx : (m == 1) ? Wy : Wz;
        WtH[r] = (_Float16)gld(dt, s, c * 32 + o);   // Wt[m][o][c] = W[c][o]
    } else if (r < 3168) {
        int q2 = r - 3072;
        int m = q2 >> 5, c = q2 & 31;
        const void* s = (m == 0) ? bx : (m == 1) ? by : bz;
        bv[q2] = gld(dt, s, c);
    } else if (r < 11360) {
        int idx = r - 3168;                 // j*64 + i
        int j = idx >> 6, i = idx & 63;
        W1H[idx] = (i < 40) ? (_Float16)gld(dt, W1, i * 128 + j) : (_Float16)0.0f;
    } else if (r < 11488) {
        b1v[r - 11360] = gld(dt, b1, r - 11360);
    } else if (r < 11616) {
        W2v[r - 11488] = gld(dt, W2, r - 11488);
    } else if (r == 11616) {
        b2v[0] = gld(dt, b2, 0);
    }
}

// =====================================================================
// fused prep: grid transpose (0..1797) + weights (1798..1843)
//           + histogram partials, plain stores (1844..2099)
// =====================================================================
__global__ __launch_bounds__(256) void kp_prep_all(
    const void* __restrict__ coords,
    const void* __restrict__ lx, const void* __restrict__ ly,
    const void* __restrict__ lz,
    const void* __restrict__ pxy, const void* __restrict__ pyz,
    const void* __restrict__ pxz, const void* __restrict__ vol,
    const void* __restrict__ Wx, const void* __restrict__ bx,
    const void* __restrict__ Wy, const void* __restrict__ by,
    const void* __restrict__ Wz, const void* __restrict__ bz,
    const void* __restrict__ W1, const void* __restrict__ b1,
    const void* __restrict__ W2, const void* __restrict__ b2,
    float* __restrict__ wbase,
    u16* __restrict__ planes_s, u16* __restrict__ vol_s,
    u16* __restrict__ lines_s, unsigned int* __restrict__ part, int M)
{
    __shared__ unsigned int lh[NBUCK];
    int dt = detect_dt(coords);
    int blk = blockIdx.x;
    if (blk < 1798) {
        int t = blk * 256 + threadIdx.x;   // [0, 460288)
        u16x8 v;
        if (t < 196608) {                 // planes: 8 consecutive out u16
            int o = t * 8;
            int pl = o >> 19;
            int r  = o & 524287;
            int pos = r >> 5, c0 = r & 31;
            const void* src = (pl == 0) ? pxy : (pl == 1) ? pyz : pxz;
#pragma unroll
            for (int i = 0; i < 8; ++i)
                v[i] = dt ? f2bf(((const float*)src)[(c0 + i) * 16384 + pos])
                          : ((const u16*)src)[(c0 + i) * 16384 + pos];
            *(u16x8*)(planes_s + o) = v;
        } else if (t < 458752) {          // volume: thread = one pos, 8 channels
            int pos = t - 196608;
#pragma unroll
            for (int c = 0; c < 8; ++c)
                v[c] = dt ? f2bf(((const float*)vol)[c * 262144 + pos])
                          : ((const u16*)vol)[c * 262144 + pos];
            *(u16x8*)(vol_s + pos * 8) = v;
        } else {                          // lines
            int o = (t - 458752) * 8;
            int l = o >> 12, rr = o & 4095;
            int pos = rr >> 5, c0 = rr & 31;
            const void* src = (l == 0) ? lx : (l == 1) ? ly : lz;
#pragma unroll
            for (int i = 0; i < 8; ++i)
                v[i] = dt ? f2bf(((const float*)src)[(c0 + i) * 128 + pos])
                          : ((const u16*)src)[(c0 + i) * 128 + pos];
            *(u16x8*)(lines_s + o) = v;
        }
    } else if (blk < 1844) {
        int r = (blk - 1798) * 256 + threadIdx.x;   // [0, 11776)
        weights_work(dt, r, Wx, bx, Wy, by, Wz, bz, W1, b1, W2, b2, wbase);
    } else {
        int b = blk - 1844;               // [0, 256)
        for (int i = threadIdx.x; i < NBUCK; i += 256) lh[i] = 0u;
        __syncthreads();
        for (int p = b * 256 + threadIdx.x; p < M; p += HBLOCKS * 256)
            atomicAdd(&lh[make_key(dt, coords, p)], 1u);
        __syncthreads();
        for (int i = threadIdx.x; i < NBUCK; i += 256)
            part[b * NBUCK + i] = lh[i];
    }
}

// =====================================================================
// column scan: part[b][bkt] -> exclusive prefix over b (in place),
// tot[bkt] = column total. 4096 threads.
// =====================================================================
__global__ __launch_bounds__(64) void kp_colscan(
    unsigned int* __restrict__ part, unsigned int* __restrict__ tot)
{
    int bkt = blockIdx.x * 64 + threadIdx.x;   // 64 blocks x 64
    unsigned int run = 0;
#pragma unroll 4
    for (int k = 0; k < HBLOCKS; ++k) {
        unsigned int v = part[k * NBUCK + bkt];
        part[k * NBUCK + bkt] = run;
        run += v;
    }
    tot[bkt] = run;
}

// =====================================================================
// deterministic scatter: 256 blocks, LDS counters, no global atomics.
// Block b walks same range as hist block b.
// =====================================================================
__global__ __launch_bounds__(256) void kp_scatter_det(
    const void* __restrict__ coords, const unsigned int* __restrict__ part,
    const unsigned int* __restrict__ tot,
    int* __restrict__ order, int M)
{
    __shared__ unsigned int cnt[NBUCK];
    __shared__ unsigned int psum[256];
    int b = blockIdx.x;          // [0, 256)
    int t = threadIdx.x;
    unsigned int bs[16];
    unsigned int s = 0;
#pragma unroll
    for (int i = 0; i < 16; ++i) {
        bs[i] = tot[t * 16 + i];
        s += bs[i];
    }
    psum[t] = s;
    __syncthreads();
    if (t == 0) {
        unsigned int run = 0;
        for (int i = 0; i < 256; ++i) { unsigned int v = psum[i]; psum[i] = run; run += v; }
    }
    __syncthreads();
    unsigned int run = psum[t];
#pragma unroll
    for (int i = 0; i < 16; ++i) {
        int bkt = t * 16 + i;
        cnt[bkt] = run + part[b * NBUCK + bkt];
        run += bs[i];
    }
    __syncthreads();
    int dt = detect_dt(coords);
    for (int p = b * 256 + t; p < M; p += HBLOCKS * 256) {
        int key = make_key(dt, coords, p);
        unsigned int pos = atomicAdd(&cnt[key], 1u);
        order[pos] = p;
    }
}

// =====================================================================
// shared math
// =====================================================================
struct Samp { int i0, i1; float w0, w1; };

static __device__ __forceinline__ Samp make_samp(float g, int N) {
    float ix = (g + 1.0f) * 0.5f * (float)(N - 1);
    float fl = floorf(ix);
    float w  = ix - fl;
    int i  = (int)fl;
    int i1 = i + 1;
    float v0 = (i  >= 0 && i  < N) ? 1.0f : 0.0f;
    float v1 = (i1 >= 0 && i1 < N) ? 1.0f : 0.0f;
    Samp s;
    s.w0 = (1.0f - w) * v0;
    s.w1 = w * v1;
    s.i0 = min(max(i, 0), N - 1);
    s.i1 = min(max(i1, 0), N - 1);
    return s;
}

#define MFMA16(a, b, c) __builtin_amdgcn_mfma_f32_16x16x32_f16((a), (b), (c), 0, 0, 0)

#define SRE 40
#define SR2 72

// one product term: interp -> LDS E (f16, relu'd) -> MFMA ta,tb -> feat += ta*tb
static __device__ __forceinline__ void term_mfma(
    int lane, const u16* __restrict__ Ls, const Samp& sl,
    const u16* __restrict__ Ps, const Samp& sa, const Samp& sb,
    const _Float16* __restrict__ Wt, const float* __restrict__ bvt,
    _Float16* El, _Float16* Ep, float (&feat)[4][2][4])
{
    int q = lane >> 4, l15 = lane & 15;
    const u16x8* l0  = (const u16x8*)(Ls + sl.i0 * 32);
    const u16x8* l1  = (const u16x8*)(Ls + sl.i1 * 32);
    const u16x8* p00 = (const u16x8*)(Ps + (sb.i0 * 128 + sa.i0) * 32);
    const u16x8* p01 = (const u16x8*)(Ps + (sb.i0 * 128 + sa.i1) * 32);
    const u16x8* p10 = (const u16x8*)(Ps + (sb.i1 * 128 + sa.i0) * 32);
    const u16x8* p11 = (const u16x8*)(Ps + (sb.i1 * 128 + sa.i1) * 32);
    float w00 = sb.w0 * sa.w0, w01 = sb.w0 * sa.w1;
    float w10 = sb.w1 * sa.w0, w11 = sb.w1 * sa.w1;
#pragma unroll
    for (int cc = 0; cc < 4; ++cc) {
        u16x8 A0 = l0[cc], A1 = l1[cc];
        u16x8 Q00 = p00[cc], Q01 = p01[cc], Q10 = p10[cc], Q11 = p11[cc];
        H8 hl, hp;
#pragma unroll
        for (int kk = 0; kk < 4; ++kk) {
            int k0 = 2 * kk, k1 = k0 + 1;
            float el0 = sl.w0 * bf2f(A0[k0]) + sl.w1 * bf2f(A1[k0]);
            float el1 = sl.w0 * bf2f(A0[k1]) + sl.w1 * bf2f(A1[k1]);
            float ep0 = w00 * bf2f(Q00[k0]) + w01 * bf2f(Q01[k0])
                      + w10 * bf2f(Q10[k0]) + w11 * bf2f(Q11[k0]);
            float ep1 = w00 * bf2f(Q00[k1]) + w01 * bf2f(Q01[k1])
                      + w10 * bf2f(Q10[k1]) + w11 * bf2f(Q11[k1]);
            hl.p[kk] = pk(fmaxf(el0, 0.0f), fmaxf(el1, 0.0f));
            hp.p[kk] = pk(fmaxf(ep0, 0.0f), fmaxf(ep1, 0.0f));
        }
        *(h8v*)&El[lane * SRE + cc * 8] = hl.v;
        *(h8v*)&Ep[lane * SRE + cc * 8] = hp.v;
    }
    __syncthreads();
    h8v bf0 = *(const h8v*)&Wt[(l15) * 32 + q * 8];
    h8v bf1 = *(const h8v*)&Wt[(16 + l15) * 32 + q * 8];
    float bb0 = bvt[l15], bb1 = bvt[16 + l15];
    f4v c0 = {bb0, bb0, bb0, bb0};
    f4v c1 = {bb1, bb1, bb1, bb1};
#pragma unroll
    for (int mt = 0; mt < 4; ++mt) {
        h8v aL = *(const h8v*)&El[(mt * 16 + l15) * SRE + q * 8];
        h8v aP = *(const h8v*)&Ep[(mt * 16 + l15) * SRE + q * 8];
        f4v ta0 = MFMA16(aL, bf0, c0);
        f4v tb0 = MFMA16(aP, bf0, c0);
        f4v ta1 = MFMA16(aL, bf1, c1);
        f4v tb1 = MFMA16(aP, bf1, c1);
#pragma unroll
        for (int r = 0; r < 4; ++r) {
            feat[mt][0][r] += ta0[r] * tb0[r];
            feat[mt][1][r] += ta1[r] * tb1[r];
        }
    }
    __syncthreads();
}

// =====================================================================
// MFMA main
// =====================================================================
__global__ __launch_bounds__(256) void kp_main_mfma(
    const void* __restrict__ coords, const int* __restrict__ order,
    const u16* __restrict__ planes_s, const u16* __restrict__ vol_s,
    const u16* __restrict__ lines_s,
    const float* __restrict__ wbase,
    void* __restrict__ out, int M)
{
    __shared__ _Float16 eb[4][5120];
    __shared__ float res[4][64];
    int dt = detect_dt(coords);
    const _Float16* WtH = (const _Float16*)wbase;
    const float*    bv  = wbase + 1536;
    const _Float16* W1H = (const _Float16*)(wbase + 1632);
    const float*    b1v = wbase + 5728;
    const float*    W2v = wbase + 5856;
    const float*    b2v = wbase + 5984;

    int tid = threadIdx.x;
    int wid = tid >> 6, lane = tid & 63;
    int q = lane >> 4, l15 = lane & 15;
    _Float16* El = eb[wid];
    _Float16* Ep = eb[wid] + 2560;
    _Float16* E2 = eb[wid];

    int p = blockIdx.x * 256 + tid;
    p = min(p, M - 1);
    int sp = order[p];

    float x = gld(dt, coords, sp * 3 + 0);
    float y = gld(dt, coords, sp * 3 + 1);
    float z = gld(dt, coords, sp * 3 + 2);

    Samp sx = make_samp(x, 128), sy = make_samp(y, 128), sz = make_samp(z, 128);

    float feat[4][2][4];
#pragma unroll
    for (int mt = 0; mt < 4; ++mt)
#pragma unroll
        for (int n = 0; n < 2; ++n)
#pragma unroll
            for (int r = 0; r < 4; ++r) feat[mt][n][r] = 0.0f;

    term_mfma(lane, lines_s + 0 * 4096, sx, planes_s + 1 * 524288, sy, sz,
              WtH + 0,    bv + 0,  El, Ep, feat);
    term_mfma(lane, lines_s + 1 * 4096, sy, planes_s + 2 * 524288, sx, sz,
              WtH + 1024, bv + 32, El, Ep, feat);
    term_mfma(lane, lines_s + 2 * 4096, sz, planes_s + 0 * 524288, sx, sy,
              WtH + 2048, bv + 64, El, Ep, feat);

#pragma unroll
    for (int mt = 0; mt < 4; ++mt)
#pragma unroll
        for (int n = 0; n < 2; ++n)
#pragma unroll
            for (int r = 0; r < 4; ++r)
                E2[(mt * 16 + q * 4 + r) * SR2 + n * 16 + l15] =
                    (_Float16)feat[mt][n][r];
    {
        Samp vx = make_samp(x, 64), vy = make_samp(y, 64), vz = make_samp(z, 64);
        float vf[8];
#pragma unroll
        for (int c = 0; c < 8; ++c) vf[c] = 0.0f;
#pragma unroll
        for (int corner = 0; corner < 8; ++corner) {
            int dx = corner & 1, dy = (corner >> 1) & 1, dz = corner >> 2;
            int xi = dx ? vx.i1 : vx.i0;
            int yi = dy ? vy.i1 : vy.i0;
            int zi = dz ? vz.i1 : vz.i0;
            float w = (dx ? vx.w1 : vx.w0) * (dy ? vy.w1 : vy.w0) * (dz ? vz.w1 : vz.w0);
            u16x8 v = *(const u16x8*)(vol_s + (((zi * 64) + yi) * 64 + xi) * 8);
#pragma unroll
            for (int c = 0; c < 8; ++c)
                vf[c] = fmaf(w, bf2f(v[c]), vf[c]);
        }
        H8 hv;
#pragma unroll
        for (int k = 0; k < 4; ++k) hv.p[k] = pk(vf[2 * k], vf[2 * k + 1]);
        *(h8v*)&E2[lane * SR2 + 32] = hv.v;
        h8v zz = {};
        *(h8v*)&E2[lane * SR2 + 40] = zz;
        *(h8v*)&E2[lane * SR2 + 48] = zz;
        *(h8v*)&E2[lane * SR2 + 56] = zz;
    }
    __syncthreads();

    h8v af[4][2];
#pragma unroll
    for (int mt = 0; mt < 4; ++mt)
#pragma unroll
        for (int ks = 0; ks < 2; ++ks)
            af[mt][ks] = *(const h8v*)&E2[(mt * 16 + l15) * SR2 + ks * 32 + q * 8];

    float s[4][4];
#pragma unroll
    for (int mt = 0; mt < 4; ++mt)
#pragma unroll
        for (int r = 0; r < 4; ++r) s[mt][r] = 0.0f;

#pragma unroll
    for (int NT = 0; NT < 8; ++NT) {
        int o = NT * 16 + l15;
        h8v b0 = *(const h8v*)&W1H[o * 64 + q * 8];
        h8v b1f = *(const h8v*)&W1H[o * 64 + 32 + q * 8];
        float w2 = W2v[o];
        float bb = b1v[o];
        f4v cinit = {bb, bb, bb, bb};
#pragma unroll
        for (int mt = 0; mt < 4; ++mt) {
            f4v c = MFMA16(af[mt][0], b0, cinit);
            c = MFMA16(af[mt][1], b1f, c);
#pragma unroll
            for (int r = 0; r < 4; ++r)
                s[mt][r] = fmaf(fmaxf(c[r], 0.0f), w2, s[mt][r]);
        }
    }
#pragma unroll
    for (int mt = 0; mt < 4; ++mt)
#pragma unroll
        for (int r = 0; r < 4; ++r) {
            float v = s[mt][r];
            v += __shfl_xor(v, 1);
            v += __shfl_xor(v, 2);
            v += __shfl_xor(v, 4);
            v += __shfl_xor(v, 8);
            s[mt][r] = v;
        }
    if (l15 == 0) {
#pragma unroll
        for (int mt = 0; mt < 4; ++mt)
#pragma unroll
            for (int r = 0; r < 4; ++r)
                res[wid][mt * 16 + q * 4 + r] = s[mt][r];
    }
    __syncthreads();
    float rr = res[wid][lane] + b2v[0];
    if (dt) ((float*)out)[sp] = rr;
    else    ((u16*)out)[sp] = f2bf(rr);
}

// =====================================================================
// fallback path (ws too small): weights-only prep + direct gathers
// =====================================================================
__global__ void kp_prep_weights_fb(
    const void* __restrict__ coords,
    const void* __restrict__ Wx, const void* __restrict__ bx,
    const void* __restrict__ Wy, const void* __restrict__ by,
    const void* __restrict__ Wz, const void* __restrict__ bz,
    const void* __restrict__ W1, const void* __restrict__ b1,
    const void* __restrict__ W2, const void* __restrict__ b2,
    float* __restrict__ wbase)
{
    int dt = detect_dt(coords);
    int t = blockIdx.x * blockDim.x + threadIdx.x;
    weights_work(dt, t, Wx, bx, Wy, by, Wz, bz, W1, b1, W2, b2, wbase);
}

__global__ __launch_bounds__(256) void kp_main_direct(
    const void* __restrict__ coords,
    const void* __restrict__ lx, const void* __restrict__ ly, const void* __restrict__ lz,
    const void* __restrict__ pxy, const void* __restrict__ pyz, const void* __restrict__ pxz,
    const void* __restrict__ vol,
    const float* __restrict__ wbase,
    void* __restrict__ out, int M)
{
    int dt = detect_dt(coords);
    const _Float16* WtH = (const _Float16*)wbase;
    const float*    bv  = wbase + 1536;
    const _Float16* W1H = (const _Float16*)(wbase + 1632);
    const float*    b1v = wbase + 5728;
    const float*    W2v = wbase + 5856;
    const float*    b2v = wbase + 5984;

    int p = blockIdx.x * 256 + threadIdx.x;
    p = min(p, M - 1);

    float x = gld(dt, coords, p * 3 + 0);
    float y = gld(dt, coords, p * 3 + 1);
    float z = gld(dt, coords, p * 3 + 2);

    Samp sx = make_samp(x, 128), sy = make_samp(y, 128), sz = make_samp(z, 128);

    float feat[40];
#pragma unroll
    for (int o = 0; o < 40; ++o) feat[o] = 0.0f;

    const void* Ls[3] = {lx, ly, lz};
    const void* Psv[3] = {pyz, pxz, pxy};
    Samp sl3[3] = {sx, sy, sz};
    Samp sa3[3] = {sy, sx, sx};
    Samp sb3[3] = {sz, sz, sy};
#pragma unroll 1
    for (int m = 0; m < 3; ++m) {
        float ta[32], tb[32];
        const float* bvt = bv + m * 32;
        const _Float16* Wt = WtH + m * 1024;
#pragma unroll
        for (int o = 0; o < 32; ++o) { ta[o] = bvt[o]; tb[o] = bvt[o]; }
        Samp sl = sl3[m], sa = sa3[m], sb = sb3[m];
        float w00 = sb.w0 * sa.w0, w01 = sb.w0 * sa.w1;
        float w10 = sb.w1 * sa.w0, w11 = sb.w1 * sa.w1;
        int i00 = sb.i0 * 128 + sa.i0, i01 = sb.i0 * 128 + sa.i1;
        int i10 = sb.i1 * 128 + sa.i0, i11 = sb.i1 * 128 + sa.i1;
#pragma unroll 1
        for (int c = 0; c < 32; ++c) {
            float el = sl.w0 * gld(dt, Ls[m], c * 128 + sl.i0)
                     + sl.w1 * gld(dt, Ls[m], c * 128 + sl.i1);
            float ep = w00 * gld(dt, Psv[m], c * 16384 + i00)
                     + w01 * gld(dt, Psv[m], c * 16384 + i01)
                     + w10 * gld(dt, Psv[m], c * 16384 + i10)
                     + w11 * gld(dt, Psv[m], c * 16384 + i11);
            float r1 = fmaxf(el, 0.0f), r2 = fmaxf(ep, 0.0f);
#pragma unroll
            for (int o = 0; o < 32; ++o) {
                float w = (float)Wt[o * 32 + c];
                ta[o] = fmaf(r1, w, ta[o]);
                tb[o] = fmaf(r2, w, tb[o]);
            }
        }
#pragma unroll
        for (int o = 0; o < 32; ++o) feat[o] = fmaf(ta[o], tb[o], feat[o]);
    }

    Samp vx = make_samp(x, 64), vy = make_samp(y, 64), vz = make_samp(z, 64);
#pragma unroll 1
    for (int corner = 0; corner < 8; ++corner) {
        int dx = corner & 1, dy = (corner >> 1) & 1, dz = corner >> 2;
        int xi = dx ? vx.i1 : vx.i0;
        int yi = dy ? vy.i1 : vy.i0;
        int zi = dz ? vz.i1 : vz.i0;
        float w = (dx ? vx.w1 : vx.w0) * (dy ? vy.w1 : vy.w0) * (dz ? vz.w1 : vz.w0);
        int pos = ((zi * 64) + yi) * 64 + xi;
#pragma unroll
        for (int c = 0; c < 8; ++c)
            feat[32 + c] = fmaf(w, gld(dt, vol, c * 262144 + pos), feat[32 + c]);
    }

    float acc_out = b2v[0];
#pragma unroll 2
    for (int j = 0; j < 128; ++j) {
        float acc = b1v[j];
        const _Float16* wr = W1H + j * 64;
#pragma unroll
        for (int i = 0; i < 40; ++i)
            acc = fmaf(feat[i], (float)wr[i], acc);
        acc_out = fmaf(fmaxf(acc, 0.0f), W2v[j], acc_out);
    }
    if (dt) ((float*)out)[p] = acc_out;
    else    ((u16*)out)[p] = f2bf(acc_out);
}

// =====================================================================
extern "C" void kernel_launch(void* const* d_in, const int* in_sizes, int n_in,
                              void* d_out, int out_size, void* d_ws, size_t ws_size,
                              hipStream_t stream) {
    const void* coords = d_in[0];
    const void* lx  = d_in[1];
    const void* ly  = d_in[2];
    const void* lz  = d_in[3];
    const void* pxy = d_in[4];
    const void* pyz = d_in[5];
    const void* pxz = d_in[6];
    const void* vol = d_in[7];
    const void* Wx  = d_in[8];
    const void* bx  = d_in[9];
    const void* Wy  = d_in[10];
    const void* by  = d_in[11];
    const void* Wz  = d_in[12];
    const void* bz  = d_in[13];
    const void* W1  = d_in[14];
    const void* b1  = d_in[15];
    const void* W2  = d_in[16];
    const void* b2  = d_in[17];

    int M = in_sizes[0] / 3;

    char* ws = (char*)d_ws;
    float*        wbase    = (float*)(ws + WF_OFF);
    u16*          planes_s = (u16*)(ws + PLANES_S_OFF);
    u16*          vol_s    = (u16*)(ws + VOL_S_OFF);
    u16*          lines_s  = (u16*)(ws + LINES_S_OFF);
    unsigned int* part     = (unsigned int*)(ws + PART_OFF);
    unsigned int* tot      = (unsigned int*)(ws + TOT_OFF);
    int*          order    = (int*)(ws + ORDER_OFF);

    size_t need_sorted = (size_t)ORDER_OFF + (size_t)M * 4u;

    int blocks = (M + 255) / 256;
    if (ws_size >= need_sorted) {
        kp_prep_all<<<2100, 256, 0, stream>>>(coords, lx, ly, lz, pxy, pyz, pxz, vol,
                                              Wx, bx, Wy, by, Wz, bz, W1, b1, W2, b2,
                                              wbase, planes_s, vol_s, lines_s, part, M);
        kp_colscan<<<64, 64, 0, stream>>>(part, tot);
        kp_scatter_det<<<HBLOCKS, 256, 0, stream>>>(coords, part, tot, order, M);
        kp_main_mfma<<<blocks, 256, 0, stream>>>(coords, order, planes_s, vol_s,
                                                 lines_s, wbase, d_out, M);
    } else {
        kp_prep_weights_fb<<<46, 256, 0, stream>>>(coords, Wx, bx, Wy, by, Wz, bz,
                                                   W1, b1, W2, b2, wbase);
        kp_main_direct<<<blocks, 256, 0, stream>>>(coords, lx, ly, lz, pxy, pyz, pxz,
                                                   vol, wbase, d_out, M);
    }
}

// Round 10
// 203.741 us; speedup vs baseline: 1.5720x; 1.0744x over previous
//
#include <hip/hip_runtime.h>

typedef unsigned short u16;
typedef u16 u16x8 __attribute__((ext_vector_type(8)));
typedef _Float16 half2 __attribute__((ext_vector_type(2)));
typedef _Float16 h8v __attribute__((ext_vector_type(8)));
typedef float f4v __attribute__((ext_vector_type(4)));

union H8 { h8v v; half2 p[4]; };

// ---------- bf16 helpers ----------
static __device__ __forceinline__ float bf2f(u16 u) {
    union { unsigned int i; float f; } v;
    v.i = ((unsigned int)u) << 16;
    return v.f;
}
static __device__ __forceinline__ u16 f2bf(float f) {
    union { float f; unsigned int i; } v;
    v.f = f;
    unsigned int x = v.i;
    x += 0x7fffu + ((x >> 16) & 1u);   // RNE
    return (u16)(x >> 16);
}
static __device__ __forceinline__ float gld(int dt, const void* p, int i) {
    return dt ? ((const float*)p)[i] : bf2f(((const u16*)p)[i]);
}
static __device__ __forceinline__ int detect_dt(const void* coords) {
    u16 v = ((const u16*)coords)[threadIdx.x & 63];
    int e = (v >> 7) & 0xFF;
    bool inr = (e >= 90) && (e <= 126);
    unsigned long long m = __ballot(inr);
    return (__popcll(m) >= 56) ? 0 : 1;   // 0=bf16, 1=f32
}
static __device__ __forceinline__ half2 pk(float a, float b) {
    return __builtin_bit_cast(half2, __builtin_amdgcn_cvt_pkrtz(a, b));
}

// ---------- ws layout (bytes) ----------
#define WF_OFF        64u
#define PLANES_S_OFF  34304u         // 3*524288 u16
#define VOL_S_OFF     3180032u       // 2097152 u16
#define LINES_S_OFF   7374336u       // 12288 u16
#define PART_OFF      7398912u       // 256*4096 u32 = 4 MB
#define TOT_OFF       11593216u      // 4096 u32
#define ORDER_OFF     11609600u      // 4*M

#define NBUCK 4096
#define HBLOCKS 256

// weight region (float units from wbase):
//   Wt  f16[3][32 o][32 c]   | bv f32[96] | W1t f16[128][64 pad]
//   b1v f32[128] | W2v f32[128] | b2v f32[1]

// =====================================================================
// spatial key
// =====================================================================
static __device__ __forceinline__ int make_key(int dt, const void* coords, int p) {
    float x = gld(dt, coords, p * 3 + 0);
    float y = gld(dt, coords, p * 3 + 1);
    float z = gld(dt, coords, p * 3 + 2);
    int kx = min(max((int)((x + 1.0f) * 8.0f), 0), 15);
    int ky = min(max((int)((y + 1.0f) * 8.0f), 0), 15);
    int kz = min(max((int)((z + 1.0f) * 8.0f), 0), 15);
    return (kz * 16 + ky) * 16 + kx;
}

// =====================================================================
// weight packing (f16 MFMA layouts)
// =====================================================================
static __device__ __forceinline__ void weights_work(
    int dt, int r,
    const void* Wx, const void* bx, const void* Wy, const void* by,
    const void* Wz, const void* bz, const void* W1, const void* b1,
    const void* W2, const void* b2, float* wbase)
{
    _Float16* WtH = (_Float16*)wbase;
    float*    bv  = wbase + 1536;
    _Float16* W1H = (_Float16*)(wbase + 1632);
    float*    b1v = wbase + 5728;
    float*    W2v = wbase + 5856;
    float*    b2v = wbase + 5984;
    if (r < 3072) {
        int m = r >> 10, idx = r & 1023;
        int o = idx >> 5, c = idx & 31;
        const void* s = (m == 0) ? Wx : (m == 1) ? Wy : Wz;
        WtH[r] = (_Float16)gld(dt, s, c * 32 + o);   // Wt[m][o][c] = W[c][o]
    } else if (r < 3168) {
        int q2 = r - 3072;
        int m = q2 >> 5, c = q2 & 31;
        const void* s = (m == 0) ? bx : (m == 1) ? by : bz;
        bv[q2] = gld(dt, s, c);
    } else if (r < 11360) {
        int idx = r - 3168;                 // j*64 + i
        int j = idx >> 6, i = idx & 63;
        W1H[idx] = (i < 40) ? (_Float16)gld(dt, W1, i * 128 + j) : (_Float16)0.0f;
    } else if (r < 11488) {
        b1v[r - 11360] = gld(dt, b1, r - 11360);
    } else if (r < 11616) {
        W2v[r - 11488] = gld(dt, W2, r - 11488);
    } else if (r == 11616) {
        b2v[0] = gld(dt, b2, 0);
    }
}

// =====================================================================
// fused prep: grid transpose (0..1797) + weights (1798..1843)
//           + histogram partials, plain stores (1844..2099)
// =====================================================================
__global__ __launch_bounds__(256) void kp_prep_all(
    const void* __restrict__ coords,
    const void* __restrict__ lx, const void* __restrict__ ly,
    const void* __restrict__ lz,
    const void* __restrict__ pxy, const void* __restrict__ pyz,
    const void* __restrict__ pxz, const void* __restrict__ vol,
    const void* __restrict__ Wx, const void* __restrict__ bx,
    const void* __restrict__ Wy, const void* __restrict__ by,
    const void* __restrict__ Wz, const void* __restrict__ bz,
    const void* __restrict__ W1, const void* __restrict__ b1,
    const void* __restrict__ W2, const void* __restrict__ b2,
    float* __restrict__ wbase,
    u16* __restrict__ planes_s, u16* __restrict__ vol_s,
    u16* __restrict__ lines_s, unsigned int* __restrict__ part, int M)
{
    __shared__ unsigned int lh[NBUCK];
    int dt = detect_dt(coords);
    int blk = blockIdx.x;
    if (blk < 1798) {
        int t = blk * 256 + threadIdx.x;   // [0, 460288)
        u16x8 v;
        if (t < 196608) {                 // planes: 8 consecutive out u16
            int o = t * 8;
            int pl = o >> 19;
            int r  = o & 524287;
            int pos = r >> 5, c0 = r & 31;
            const void* src = (pl == 0) ? pxy : (pl == 1) ? pyz : pxz;
#pragma unroll
            for (int i = 0; i < 8; ++i)
                v[i] = dt ? f2bf(((const float*)src)[(c0 + i) * 16384 + pos])
                          : ((const u16*)src)[(c0 + i) * 16384 + pos];
            *(u16x8*)(planes_s + o) = v;
        } else if (t < 458752) {          // volume: thread = one pos, 8 channels
            int pos = t - 196608;
#pragma unroll
            for (int c = 0; c < 8; ++c)
                v[c] = dt ? f2bf(((const float*)vol)[c * 262144 + pos])
                          : ((const u16*)vol)[c * 262144 + pos];
            *(u16x8*)(vol_s + pos * 8) = v;
        } else {                          // lines
            int o = (t - 458752) * 8;
            int l = o >> 12, rr = o & 4095;
            int pos = rr >> 5, c0 = rr & 31;
            const void* src = (l == 0) ? lx : (l == 1) ? ly : lz;
#pragma unroll
            for (int i = 0; i < 8; ++i)
                v[i] = dt ? f2bf(((const float*)src)[(c0 + i) * 128 + pos])
                          : ((const u16*)src)[(c0 + i) * 128 + pos];
            *(u16x8*)(lines_s + o) = v;
        }
    } else if (blk < 1844) {
        int r = (blk - 1798) * 256 + threadIdx.x;   // [0, 11776)
        weights_work(dt, r, Wx, bx, Wy, by, Wz, bz, W1, b1, W2, b2, wbase);
    } else {
        int b = blk - 1844;               // [0, 256)
        for (int i = threadIdx.x; i < NBUCK; i += 256) lh[i] = 0u;
        __syncthreads();
        for (int p = b * 256 + threadIdx.x; p < M; p += HBLOCKS * 256)
            atomicAdd(&lh[make_key(dt, coords, p)], 1u);
        __syncthreads();
        for (int i = threadIdx.x; i < NBUCK; i += 256)
            part[b * NBUCK + i] = lh[i];
    }
}

// =====================================================================
// column scan: part[b][bkt] -> exclusive prefix over b (in place),
// tot[bkt] = column total. 4096 threads.
// =====================================================================
__global__ __launch_bounds__(64) void kp_colscan(
    unsigned int* __restrict__ part, unsigned int* __restrict__ tot)
{
    int bkt = blockIdx.x * 64 + threadIdx.x;   // 64 blocks x 64
    unsigned int run = 0;
#pragma unroll 8
    for (int k = 0; k < HBLOCKS; ++k) {
        unsigned int v = part[k * NBUCK + bkt];
        part[k * NBUCK + bkt] = run;
        run += v;
    }
    tot[bkt] = run;
}

// =====================================================================
// deterministic scatter: 256 blocks, LDS counters, no global atomics.
// =====================================================================
__global__ __launch_bounds__(256) void kp_scatter_det(
    const void* __restrict__ coords, const unsigned int* __restrict__ part,
    const unsigned int* __restrict__ tot,
    int* __restrict__ order, int M)
{
    __shared__ unsigned int cnt[NBUCK];
    __shared__ unsigned int psum[256];
    int b = blockIdx.x;          // [0, 256)
    int t = threadIdx.x;
    unsigned int bs[16];
    unsigned int s = 0;
#pragma unroll
    for (int i = 0; i < 16; ++i) {
        bs[i] = tot[t * 16 + i];
        s += bs[i];
    }
    psum[t] = s;
    __syncthreads();
    if (t == 0) {
        unsigned int run = 0;
        for (int i = 0; i < 256; ++i) { unsigned int v = psum[i]; psum[i] = run; run += v; }
    }
    __syncthreads();
    unsigned int run = psum[t];
#pragma unroll
    for (int i = 0; i < 16; ++i) {
        int bkt = t * 16 + i;
        cnt[bkt] = run + part[b * NBUCK + bkt];
        run += bs[i];
    }
    __syncthreads();
    int dt = detect_dt(coords);
    for (int p = b * 256 + t; p < M; p += HBLOCKS * 256) {
        int key = make_key(dt, coords, p);
        unsigned int pos = atomicAdd(&cnt[key], 1u);
        order[pos] = p;
    }
}

// =====================================================================
// shared math
// =====================================================================
struct Samp { int i0, i1; float w0, w1; };

static __device__ __forceinline__ Samp make_samp(float g, int N) {
    float ix = (g + 1.0f) * 0.5f * (float)(N - 1);
    float fl = floorf(ix);
    float w  = ix - fl;
    int i  = (int)fl;
    int i1 = i + 1;
    float v0 = (i  >= 0 && i  < N) ? 1.0f : 0.0f;
    float v1 = (i1 >= 0 && i1 < N) ? 1.0f : 0.0f;
    Samp s;
    s.w0 = (1.0f - w) * v0;
    s.w1 = w * v1;
    s.i0 = min(max(i, 0), N - 1);
    s.i1 = min(max(i1, 0), N - 1);
    return s;
}

#define MFMA16(a, b, c) __builtin_amdgcn_mfma_f32_16x16x32_f16((a), (b), (c), 0, 0, 0)

#define SRE 40
#define SR2 72

// one product term: interp -> LDS E (f16, relu'd) -> MFMA ta,tb -> feat += ta*tb
// single-wave workgroup: __syncthreads is a 1-wave barrier (cheap)
static __device__ __forceinline__ void term_mfma(
    int lane, const u16* __restrict__ Ls, const Samp& sl,
    const u16* __restrict__ Ps, const Samp& sa, const Samp& sb,
    const _Float16* __restrict__ Wt, const float* __restrict__ bvt,
    _Float16* El, _Float16* Ep, float (&feat)[4][2][4])
{
    int q = lane >> 4, l15 = lane & 15;
    const u16x8* l0  = (const u16x8*)(Ls + sl.i0 * 32);
    const u16x8* l1  = (const u16x8*)(Ls + sl.i1 * 32);
    const u16x8* p00 = (const u16x8*)(Ps + (sb.i0 * 128 + sa.i0) * 32);
    const u16x8* p01 = (const u16x8*)(Ps + (sb.i0 * 128 + sa.i1) * 32);
    const u16x8* p10 = (const u16x8*)(Ps + (sb.i1 * 128 + sa.i0) * 32);
    const u16x8* p11 = (const u16x8*)(Ps + (sb.i1 * 128 + sa.i1) * 32);
    float w00 = sb.w0 * sa.w0, w01 = sb.w0 * sa.w1;
    float w10 = sb.w1 * sa.w0, w11 = sb.w1 * sa.w1;
#pragma unroll
    for (int cc = 0; cc < 4; ++cc) {
        u16x8 A0 = l0[cc], A1 = l1[cc];
        u16x8 Q00 = p00[cc], Q01 = p01[cc], Q10 = p10[cc], Q11 = p11[cc];
        H8 hl, hp;
#pragma unroll
        for (int kk = 0; kk < 4; ++kk) {
            int k0 = 2 * kk, k1 = k0 + 1;
            float el0 = sl.w0 * bf2f(A0[k0]) + sl.w1 * bf2f(A1[k0]);
            float el1 = sl.w0 * bf2f(A0[k1]) + sl.w1 * bf2f(A1[k1]);
            float ep0 = w00 * bf2f(Q00[k0]) + w01 * bf2f(Q01[k0])
                      + w10 * bf2f(Q10[k0]) + w11 * bf2f(Q11[k0]);
            float ep1 = w00 * bf2f(Q00[k1]) + w01 * bf2f(Q01[k1])
                      + w10 * bf2f(Q10[k1]) + w11 * bf2f(Q11[k1]);
            hl.p[kk] = pk(fmaxf(el0, 0.0f), fmaxf(el1, 0.0f));
            hp.p[kk] = pk(fmaxf(ep0, 0.0f), fmaxf(ep1, 0.0f));
        }
        *(h8v*)&El[lane * SRE + cc * 8] = hl.v;
        *(h8v*)&Ep[lane * SRE + cc * 8] = hp.v;
    }
    __syncthreads();
    h8v bf0 = *(const h8v*)&Wt[(l15) * 32 + q * 8];
    h8v bf1 = *(const h8v*)&Wt[(16 + l15) * 32 + q * 8];
    float bb0 = bvt[l15], bb1 = bvt[16 + l15];
    f4v c0 = {bb0, bb0, bb0, bb0};
    f4v c1 = {bb1, bb1, bb1, bb1};
#pragma unroll
    for (int mt = 0; mt < 4; ++mt) {
        h8v aL = *(const h8v*)&El[(mt * 16 + l15) * SRE + q * 8];
        h8v aP = *(const h8v*)&Ep[(mt * 16 + l15) * SRE + q * 8];
        f4v ta0 = MFMA16(aL, bf0, c0);
        f4v tb0 = MFMA16(aP, bf0, c0);
        f4v ta1 = MFMA16(aL, bf1, c1);
        f4v tb1 = MFMA16(aP, bf1, c1);
#pragma unroll
        for (int r = 0; r < 4; ++r) {
            feat[mt][0][r] += ta0[r] * tb0[r];
            feat[mt][1][r] += ta1[r] * tb1[r];
        }
    }
    __syncthreads();
}

// =====================================================================
// MFMA main — 64-thread (single-wave) blocks: barriers are wave-local,
// waves fully decoupled, LDS 10.5 KB/block -> ~15 blocks/CU
// =====================================================================
__global__ __launch_bounds__(64) void kp_main_mfma(
    const void* __restrict__ coords, const int* __restrict__ order,
    const u16* __restrict__ planes_s, const u16* __restrict__ vol_s,
    const u16* __restrict__ lines_s,
    const float* __restrict__ wbase,
    void* __restrict__ out, int M)
{
    __shared__ _Float16 eb[5120];   // El[64*40] | Ep[64*40]; reused as E2[64*72]
    __shared__ float res[64];
    int dt = detect_dt(coords);
    const _Float16* WtH = (const _Float16*)wbase;
    const float*    bv  = wbase + 1536;
    const _Float16* W1H = (const _Float16*)(wbase + 1632);
    const float*    b1v = wbase + 5728;
    const float*    W2v = wbase + 5856;
    const float*    b2v = wbase + 5984;

    int lane = threadIdx.x;
    int q = lane >> 4, l15 = lane & 15;
    _Float16* El = eb;
    _Float16* Ep = eb + 2560;
    _Float16* E2 = eb;

    int p = blockIdx.x * 64 + lane;
    p = min(p, M - 1);
    int sp = order[p];

    float x = gld(dt, coords, sp * 3 + 0);
    float y = gld(dt, coords, sp * 3 + 1);
    float z = gld(dt, coords, sp * 3 + 2);

    Samp sx = make_samp(x, 128), sy = make_samp(y, 128), sz = make_samp(z, 128);

    float feat[4][2][4];
#pragma unroll
    for (int mt = 0; mt < 4; ++mt)
#pragma unroll
        for (int n = 0; n < 2; ++n)
#pragma unroll
            for (int r = 0; r < 4; ++r) feat[mt][n][r] = 0.0f;

    term_mfma(lane, lines_s + 0 * 4096, sx, planes_s + 1 * 524288, sy, sz,
              WtH + 0,    bv + 0,  El, Ep, feat);
    term_mfma(lane, lines_s + 1 * 4096, sy, planes_s + 2 * 524288, sx, sz,
              WtH + 1024, bv + 32, El, Ep, feat);
    term_mfma(lane, lines_s + 2 * 4096, sz, planes_s + 0 * 524288, sx, sy,
              WtH + 2048, bv + 64, El, Ep, feat);

#pragma unroll
    for (int mt = 0; mt < 4; ++mt)
#pragma unroll
        for (int n = 0; n < 2; ++n)
#pragma unroll
            for (int r = 0; r < 4; ++r)
                E2[(mt * 16 + q * 4 + r) * SR2 + n * 16 + l15] =
                    (_Float16)feat[mt][n][r];
    {
        Samp vx = make_samp(x, 64), vy = make_samp(y, 64), vz = make_samp(z, 64);
        float vf[8];
#pragma unroll
        for (int c = 0; c < 8; ++c) vf[c] = 0.0f;
#pragma unroll
        for (int corner = 0; corner < 8; ++corner) {
            int dx = corner & 1, dy = (corner >> 1) & 1, dz = corner >> 2;
            int xi = dx ? vx.i1 : vx.i0;
            int yi = dy ? vy.i1 : vy.i0;
            int zi = dz ? vz.i1 : vz.i0;
            float w = (dx ? vx.w1 : vx.w0) * (dy ? vy.w1 : vy.w0) * (dz ? vz.w1 : vz.w0);
            u16x8 v = *(const u16x8*)(vol_s + (((zi * 64) + yi) * 64 + xi) * 8);
#pragma unroll
            for (int c = 0; c < 8; ++c)
                vf[c] = fmaf(w, bf2f(v[c]), vf[c]);
        }
        H8 hv;
#pragma unroll
        for (int k = 0; k < 4; ++k) hv.p[k] = pk(vf[2 * k], vf[2 * k + 1]);
        *(h8v*)&E2[lane * SR2 + 32] = hv.v;
        h8v zz = {};
        *(h8v*)&E2[lane * SR2 + 40] = zz;
        *(h8v*)&E2[lane * SR2 + 48] = zz;
        *(h8v*)&E2[lane * SR2 + 56] = zz;
    }
    __syncthreads();

    h8v af[4][2];
#pragma unroll
    for (int mt = 0; mt < 4; ++mt)
#pragma unroll
        for (int ks = 0; ks < 2; ++ks)
            af[mt][ks] = *(const h8v*)&E2[(mt * 16 + l15) * SR2 + ks * 32 + q * 8];

    float s[4][4];
#pragma unroll
    for (int mt = 0; mt < 4; ++mt)
#pragma unroll
        for (int r = 0; r < 4; ++r) s[mt][r] = 0.0f;

#pragma unroll
    for (int NT = 0; NT < 8; ++NT) {
        int o = NT * 16 + l15;
        h8v b0 = *(const h8v*)&W1H[o * 64 + q * 8];
        h8v b1f = *(const h8v*)&W1H[o * 64 + 32 + q * 8];
        float w2 = W2v[o];
        float bb = b1v[o];
        f4v cinit = {bb, bb, bb, bb};
#pragma unroll
        for (int mt = 0; mt < 4; ++mt) {
            f4v c = MFMA16(af[mt][0], b0, cinit);
            c = MFMA16(af[mt][1], b1f, c);
#pragma unroll
            for (int r = 0; r < 4; ++r)
                s[mt][r] = fmaf(fmaxf(c[r], 0.0f), w2, s[mt][r]);
        }
    }
#pragma unroll
    for (int mt = 0; mt < 4; ++mt)
#pragma unroll
        for (int r = 0; r < 4; ++r) {
            float v = s[mt][r];
            v += __shfl_xor(v, 1);
            v += __shfl_xor(v, 2);
            v += __shfl_xor(v, 4);
            v += __shfl_xor(v, 8);
            s[mt][r] = v;
        }
    if (l15 == 0) {
#pragma unroll
        for (int mt = 0; mt < 4; ++mt)
#pragma unroll
            for (int r = 0; r < 4; ++r)
                res[mt * 16 + q * 4 + r] = s[mt][r];
    }
    __syncthreads();
    float rr = res[lane] + b2v[0];
    if (dt) ((float*)out)[sp] = rr;
    else    ((u16*)out)[sp] = f2bf(rr);
}

// =====================================================================
// fallback path (ws too small): weights-only prep + direct gathers
// =====================================================================
__global__ void kp_prep_weights_fb(
    const void* __restrict__ coords,
    const void* __restrict__ Wx, const void* __restrict__ bx,
    const void* __restrict__ Wy, const void* __restrict__ by,
    const void* __restrict__ Wz, const void* __restrict__ bz,
    const void* __restrict__ W1, const void* __restrict__ b1,
    const void* __restrict__ W2, const void* __restrict__ b2,
    float* __restrict__ wbase)
{
    int dt = detect_dt(coords);
    int t = blockIdx.x * blockDim.x + threadIdx.x;
    weights_work(dt, t, Wx, bx, Wy, by, Wz, bz, W1, b1, W2, b2, wbase);
}

__global__ __launch_bounds__(256) void kp_main_direct(
    const void* __restrict__ coords,
    const void* __restrict__ lx, const void* __restrict__ ly, const void* __restrict__ lz,
    const void* __restrict__ pxy, const void* __restrict__ pyz, const void* __restrict__ pxz,
    const void* __restrict__ vol,
    const float* __restrict__ wbase,
    void* __restrict__ out, int M)
{
    int dt = detect_dt(coords);
    const _Float16* WtH = (const _Float16*)wbase;
    const float*    bv  = wbase + 1536;
    const _Float16* W1H = (const _Float16*)(wbase + 1632);
    const float*    b1v = wbase + 5728;
    const float*    W2v = wbase + 5856;
    const float*    b2v = wbase + 5984;

    int p = blockIdx.x * 256 + threadIdx.x;
    p = min(p, M - 1);

    float x = gld(dt, coords, p * 3 + 0);
    float y = gld(dt, coords, p * 3 + 1);
    float z = gld(dt, coords, p * 3 + 2);

    Samp sx = make_samp(x, 128), sy = make_samp(y, 128), sz = make_samp(z, 128);

    float feat[40];
#pragma unroll
    for (int o = 0; o < 40; ++o) feat[o] = 0.0f;

    const void* Ls[3] = {lx, ly, lz};
    const void* Psv[3] = {pyz, pxz, pxy};
    Samp sl3[3] = {sx, sy, sz};
    Samp sa3[3] = {sy, sx, sx};
    Samp sb3[3] = {sz, sz, sy};
#pragma unroll 1
    for (int m = 0; m < 3; ++m) {
        float ta[32], tb[32];
        const float* bvt = bv + m * 32;
        const _Float16* Wt = WtH + m * 1024;
#pragma unroll
        for (int o = 0; o < 32; ++o) { ta[o] = bvt[o]; tb[o] = bvt[o]; }
        Samp sl = sl3[m], sa = sa3[m], sb = sb3[m];
        float w00 = sb.w0 * sa.w0, w01 = sb.w0 * sa.w1;
        float w10 = sb.w1 * sa.w0, w11 = sb.w1 * sa.w1;
        int i00 = sb.i0 * 128 + sa.i0, i01 = sb.i0 * 128 + sa.i1;
        int i10 = sb.i1 * 128 + sa.i0, i11 = sb.i1 * 128 + sa.i1;
#pragma unroll 1
        for (int c = 0; c < 32; ++c) {
            float el = sl.w0 * gld(dt, Ls[m], c * 128 + sl.i0)
                     + sl.w1 * gld(dt, Ls[m], c * 128 + sl.i1);
            float ep = w00 * gld(dt, Psv[m], c * 16384 + i00)
                     + w01 * gld(dt, Psv[m], c * 16384 + i01)
                     + w10 * gld(dt, Psv[m], c * 16384 + i10)
                     + w11 * gld(dt, Psv[m], c * 16384 + i11);
            float r1 = fmaxf(el, 0.0f), r2 = fmaxf(ep, 0.0f);
#pragma unroll
            for (int o = 0; o < 32; ++o) {
                float w = (float)Wt[o * 32 + c];
                ta[o] = fmaf(r1, w, ta[o]);
                tb[o] = fmaf(r2, w, tb[o]);
            }
        }
#pragma unroll
        for (int o = 0; o < 32; ++o) feat[o] = fmaf(ta[o], tb[o], feat[o]);
    }

    Samp vx = make_samp(x, 64), vy = make_samp(y, 64), vz = make_samp(z, 64);
#pragma unroll 1
    for (int corner = 0; corner < 8; ++corner) {
        int dx = corner & 1, dy = (corner >> 1) & 1, dz = corner >> 2;
        int xi = dx ? vx.i1 : vx.i0;
        int yi = dy ? vy.i1 : vy.i0;
        int zi = dz ? vz.i1 : vz.i0;
        float w = (dx ? vx.w1 : vx.w0) * (dy ? vy.w1 : vy.w0) * (dz ? vz.w1 : vz.w0);
        int pos = ((zi * 64) + yi) * 64 + xi;
#pragma unroll
        for (int c = 0; c < 8; ++c)
            feat[32 + c] = fmaf(w, gld(dt, vol, c * 262144 + pos), feat[32 + c]);
    }

    float acc_out = b2v[0];
#pragma unroll 2
    for (int j = 0; j < 128; ++j) {
        float acc = b1v[j];
        const _Float16* wr = W1H + j * 64;
#pragma unroll
        for (int i = 0; i < 40; ++i)
            acc = fmaf(feat[i], (float)wr[i], acc);
        acc_out = fmaf(fmaxf(acc, 0.0f), W2v[j], acc_out);
    }
    if (dt) ((float*)out)[p] = acc_out;
    else    ((u16*)out)[p] = f2bf(acc_out);
}

// =====================================================================
extern "C" void kernel_launch(void* const* d_in, const int* in_sizes, int n_in,
                              void* d_out, int out_size, void* d_ws, size_t ws_size,
                              hipStream_t stream) {
    const void* coords = d_in[0];
    const void* lx  = d_in[1];
    const void* ly  = d_in[2];
    const void* lz  = d_in[3];
    const void* pxy = d_in[4];
    const void* pyz = d_in[5];
    const void* pxz = d_in[6];
    const void* vol = d_in[7];
    const void* Wx  = d_in[8];
    const void* bx  = d_in[9];
    const void* Wy  = d_in[10];
    const void* by  = d_in[11];
    const void* Wz  = d_in[12];
    const void* bz  = d_in[13];
    const void* W1  = d_in[14];
    const void* b1  = d_in[15];
    const void* W2  = d_in[16];
    const void* b2  = d_in[17];

    int M = in_sizes[0] / 3;

    char* ws = (char*)d_ws;
    float*        wbase    = (float*)(ws + WF_OFF);
    u16*          planes_s = (u16*)(ws + PLANES_S_OFF);
    u16*          vol_s    = (u16*)(ws + VOL_S_OFF);
    u16*          lines_s  = (u16*)(ws + LINES_S_OFF);
    unsigned int* part     = (unsigned int*)(ws + PART_OFF);
    unsigned int* tot      = (unsigned int*)(ws + TOT_OFF);
    int*          order    = (int*)(ws + ORDER_OFF);

    size_t need_sorted = (size_t)ORDER_OFF + (size_t)M * 4u;

    if (ws_size >= need_sorted) {
        kp_prep_all<<<2100, 256, 0, stream>>>(coords, lx, ly, lz, pxy, pyz, pxz, vol,
                                              Wx, bx, Wy, by, Wz, bz, W1, b1, W2, b2,
                                              wbase, planes_s, vol_s, lines_s, part, M);
        kp_colscan<<<64, 64, 0, stream>>>(part, tot);
        kp_scatter_det<<<HBLOCKS, 256, 0, stream>>>(coords, part, tot, order, M);
        int blocks64 = (M + 63) / 64;
        kp_main_mfma<<<blocks64, 64, 0, stream>>>(coords, order, planes_s, vol_s,
                                                  lines_s, wbase, d_out, M);
    } else {
        int blocks = (M + 255) / 256;
        kp_prep_weights_fb<<<46, 256, 0, stream>>>(coords, Wx, bx, Wy, by, Wz, bz,
                                                   W1, b1, W2, b2, wbase);
        kp_main_direct<<<blocks, 256, 0, stream>>>(coords, lx, ly, lz, pxy, pyz, pxz,
                                                   vol, wbase, d_out, M);
    }
}

// Round 12
// 202.656 us; speedup vs baseline: 1.5804x; 1.0054x over previous
//
#include <hip/hip_runtime.h>

typedef unsigned short u16;
typedef u16 u16x8 __attribute__((ext_vector_type(8)));
typedef _Float16 half2 __attribute__((ext_vector_type(2)));
typedef _Float16 h8v __attribute__((ext_vector_type(8)));
typedef float f4v __attribute__((ext_vector_type(4)));

union H8 { h8v v; half2 p[4]; };

// ---------- bf16 helpers ----------
static __device__ __forceinline__ float bf2f(u16 u) {
    union { unsigned int i; float f; } v;
    v.i = ((unsigned int)u) << 16;
    return v.f;
}
static __device__ __forceinline__ u16 f2bf(float f) {
    union { float f; unsigned int i; } v;
    v.f = f;
    unsigned int x = v.i;
    x += 0x7fffu + ((x >> 16) & 1u);   // RNE
    return (u16)(x >> 16);
}
static __device__ __forceinline__ float gld(int dt, const void* p, int i) {
    return dt ? ((const float*)p)[i] : bf2f(((const u16*)p)[i]);
}
static __device__ __forceinline__ int detect_dt(const void* coords) {
    u16 v = ((const u16*)coords)[threadIdx.x & 63];
    int e = (v >> 7) & 0xFF;
    bool inr = (e >= 90) && (e <= 126);
    unsigned long long m = __ballot(inr);
    return (__popcll(m) >= 56) ? 0 : 1;   // 0=bf16, 1=f32
}
static __device__ __forceinline__ half2 pk(float a, float b) {
    return __builtin_bit_cast(half2, __builtin_amdgcn_cvt_pkrtz(a, b));
}

// ---------- ws layout (bytes) ----------
#define WF_OFF        64u
#define PLANES_S_OFF  34304u         // 3*524288 u16
#define VOL_S_OFF     3180032u       // 2097152 u16
#define LINES_S_OFF   7374336u       // 12288 u16
#define PART_OFF      7398912u       // 256*4096 u16 = 2 MB
#define TOT_OFF       9496064u       // 4096 u32
#define ORDER_OFF     9512448u       // 4*M
// SCOORD_OFF = ORDER_OFF + 4*M (runtime), 6*M bytes (u16 x3)

#define NBUCK 4096
#define HBLOCKS 256

// weight region (float units from wbase):
//   Wt  f16[3][32 o][32 c]   | bv f32[96] | W1t f16[128][64 pad]
//   b1v f32[128] | W2v f32[128] | b2v f32[1]

// =====================================================================
// spatial key
// =====================================================================
static __device__ __forceinline__ int make_key3(float x, float y, float z) {
    int kx = min(max((int)((x + 1.0f) * 8.0f), 0), 15);
    int ky = min(max((int)((y + 1.0f) * 8.0f), 0), 15);
    int kz = min(max((int)((z + 1.0f) * 8.0f), 0), 15);
    return (kz * 16 + ky) * 16 + kx;
}
static __device__ __forceinline__ int make_key(int dt, const void* coords, int p) {
    return make_key3(gld(dt, coords, p * 3 + 0), gld(dt, coords, p * 3 + 1),
                     gld(dt, coords, p * 3 + 2));
}

// =====================================================================
// weight packing (f16 MFMA layouts)
// =====================================================================
static __device__ __forceinline__ void weights_work(
    int dt, int r,
    const void* Wx, const void* bx, const void* Wy, const void* by,
    const void* Wz, const void* bz, const void* W1, const void* b1,
    const void* W2, const void* b2, float* wbase)
{
    _Float16* WtH = (_Float16*)wbase;
    float*    bv  = wbase + 1536;
    _Float16* W1H = (_Float16*)(wbase + 1632);
    float*    b1v = wbase + 5728;
    float*    W2v = wbase + 5856;
    float*    b2v = wbase + 5984;
    if (r < 3072) {
        int m = r >> 10, idx = r & 1023;
        int o = idx >> 5, c = idx & 31;
        const void* s = (m == 0) ? Wx : (m == 1) ? Wy : Wz;
        WtH[r] = (_Float16)gld(dt, s, c * 32 + o);   // Wt[m][o][c] = W[c][o]
    } else if (r < 3168) {
        int q2 = r - 3072;
        int m = q2 >> 5, c = q2 & 31;
        const void* s = (m == 0) ? bx : (m == 1) ? by : bz;
        bv[q2] = gld(dt, s, c);
    } else if (r < 11360) {
        int idx = r - 3168;                 // j*64 + i
        int j = idx >> 6, i = idx & 63;
        W1H[idx] = (i < 40) ? (_Float16)gld(dt, W1, i * 128 + j) : (_Float16)0.0f;
    } else if (r < 11488) {
        b1v[r - 11360] = gld(dt, b1, r - 11360);
    } else if (r < 11616) {
        W2v[r - 11488] = gld(dt, W2, r - 11488);
    } else if (r == 11616) {
        b2v[0] = gld(dt, b2, 0);
    }
}

// =====================================================================
// fused prep: grid transpose (0..1797) + weights (1798..1843)
//           + histogram partials u16, plain stores (1844..2099)
// =====================================================================
__global__ __launch_bounds__(256) void kp_prep_all(
    const void* __restrict__ coords,
    const void* __restrict__ lx, const void* __restrict__ ly,
    const void* __restrict__ lz,
    const void* __restrict__ pxy, const void* __restrict__ pyz,
    const void* __restrict__ pxz, const void* __restrict__ vol,
    const void* __restrict__ Wx, const void* __restrict__ bx,
    const void* __restrict__ Wy, const void* __restrict__ by,
    const void* __restrict__ Wz, const void* __restrict__ bz,
    const void* __restrict__ W1, const void* __restrict__ b1,
    const void* __restrict__ W2, const void* __restrict__ b2,
    float* __restrict__ wbase,
    u16* __restrict__ planes_s, u16* __restrict__ vol_s,
    u16* __restrict__ lines_s, u16* __restrict__ part, int M)
{
    __shared__ unsigned int lh[NBUCK];
    int dt = detect_dt(coords);
    int blk = blockIdx.x;
    if (blk < 1798) {
        int t = blk * 256 + threadIdx.x;   // [0, 460288)
        u16x8 v;
        if (t < 196608) {                 // planes: 8 consecutive out u16
            int o = t * 8;
            int pl = o >> 19;
            int r  = o & 524287;
            int pos = r >> 5, c0 = r & 31;
            const void* src = (pl == 0) ? pxy : (pl == 1) ? pyz : pxz;
#pragma unroll
            for (int i = 0; i < 8; ++i)
                v[i] = dt ? f2bf(((const float*)src)[(c0 + i) * 16384 + pos])
                          : ((const u16*)src)[(c0 + i) * 16384 + pos];
            *(u16x8*)(planes_s + o) = v;
        } else if (t < 458752) {          // volume: thread = one pos, 8 channels
            int pos = t - 196608;
#pragma unroll
            for (int c = 0; c < 8; ++c)
                v[c] = dt ? f2bf(((const float*)vol)[c * 262144 + pos])
                          : ((const u16*)vol)[c * 262144 + pos];
            *(u16x8*)(vol_s + pos * 8) = v;
        } else {                          // lines
            int o = (t - 458752) * 8;
            int l = o >> 12, rr = o & 4095;
            int pos = rr >> 5, c0 = rr & 31;
            const void* src = (l == 0) ? lx : (l == 1) ? ly : lz;
#pragma unroll
            for (int i = 0; i < 8; ++i)
                v[i] = dt ? f2bf(((const float*)src)[(c0 + i) * 128 + pos])
                          : ((const u16*)src)[(c0 + i) * 128 + pos];
            *(u16x8*)(lines_s + o) = v;
        }
    } else if (blk < 1844) {
        int r = (blk - 1798) * 256 + threadIdx.x;   // [0, 11776)
        weights_work(dt, r, Wx, bx, Wy, by, Wz, bz, W1, b1, W2, b2, wbase);
    } else {
        int b = blk - 1844;               // [0, 256)
        for (int i = threadIdx.x; i < NBUCK; i += 256) lh[i] = 0u;
        __syncthreads();
        for (int p = b * 256 + threadIdx.x; p < M; p += HBLOCKS * 256)
            atomicAdd(&lh[make_key(dt, coords, p)], 1u);
        __syncthreads();
        for (int i = threadIdx.x; i < NBUCK; i += 256)
            part[b * NBUCK + i] = (u16)lh[i];
    }
}

// =====================================================================
// column scan: part[b][bkt] (u16) -> exclusive prefix over b (in place),
// tot[bkt] = column total.
// =====================================================================
__global__ __launch_bounds__(64) void kp_colscan(
    u16* __restrict__ part, unsigned int* __restrict__ tot)
{
    int bkt = blockIdx.x * 64 + threadIdx.x;   // 64 blocks x 64
    unsigned int run = 0;
#pragma unroll 8
    for (int k = 0; k < HBLOCKS; ++k) {
        unsigned int v = part[k * NBUCK + bkt];
        part[k * NBUCK + bkt] = (u16)run;
        run += v;
    }
    tot[bkt] = run;
}

// =====================================================================
// deterministic scatter: 256 blocks, LDS counters, no global atomics.
// Also emits reordered raw-bf16 coords (dt==0) for coalesced main reads.
// =====================================================================
__global__ __launch_bounds__(256) void kp_scatter_det(
    const void* __restrict__ coords, const u16* __restrict__ part,
    const unsigned int* __restrict__ tot,
    int* __restrict__ order, u16* __restrict__ scoords, int M)
{
    __shared__ unsigned int cnt[NBUCK];
    __shared__ unsigned int psum[256];
    int b = blockIdx.x;          // [0, 256)
    int t = threadIdx.x;
    unsigned int bs[16];
    unsigned int s = 0;
#pragma unroll
    for (int i = 0; i < 16; ++i) {
        bs[i] = tot[t * 16 + i];
        s += bs[i];
    }
    psum[t] = s;
    __syncthreads();
    if (t == 0) {
        unsigned int run = 0;
        for (int i = 0; i < 256; ++i) { unsigned int v = psum[i]; psum[i] = run; run += v; }
    }
    __syncthreads();
    unsigned int run = psum[t];
#pragma unroll
    for (int i = 0; i < 16; ++i) {
        int bkt = t * 16 + i;
        cnt[bkt] = run + (unsigned int)part[b * NBUCK + bkt];
        run += bs[i];
    }
    __syncthreads();
    int dt = detect_dt(coords);
    const u16* cu = (const u16*)coords;
    for (int p = b * 256 + t; p < M; p += HBLOCKS * 256) {
        float x = gld(dt, coords, p * 3 + 0);
        float y = gld(dt, coords, p * 3 + 1);
        float z = gld(dt, coords, p * 3 + 2);
        int key = make_key3(x, y, z);
        unsigned int pos = atomicAdd(&cnt[key], 1u);
        order[pos] = p;
        if (dt == 0) {
            scoords[pos * 3 + 0] = cu[p * 3 + 0];
            scoords[pos * 3 + 1] = cu[p * 3 + 1];
            scoords[pos * 3 + 2] = cu[p * 3 + 2];
        }
    }
}

// =====================================================================
// shared math
// =====================================================================
struct Samp { int i0, i1; float w0, w1; };

static __device__ __forceinline__ Samp make_samp(float g, int N) {
    float ix = (g + 1.0f) * 0.5f * (float)(N - 1);
    float fl = floorf(ix);
    float w  = ix - fl;
    int i  = (int)fl;
    int i1 = i + 1;
    float v0 = (i  >= 0 && i  < N) ? 1.0f : 0.0f;
    float v1 = (i1 >= 0 && i1 < N) ? 1.0f : 0.0f;
    Samp s;
    s.w0 = (1.0f - w) * v0;
    s.w1 = w * v1;
    s.i0 = min(max(i, 0), N - 1);
    s.i1 = min(max(i1, 0), N - 1);
    return s;
}

#define MFMA16(a, b, c) __builtin_amdgcn_mfma_f32_16x16x32_f16((a), (b), (c), 0, 0, 0)

#define SRE 40
#define SR2 72

// one product term: interp -> LDS E (f16, relu'd) -> MFMA ta,tb -> feat += ta*tb
static __device__ __forceinline__ void term_mfma(
    int lane, const u16* __restrict__ Ls, const Samp& sl,
    const u16* __restrict__ Ps, const Samp& sa, const Samp& sb,
    const _Float16* __restrict__ Wt, const float* __restrict__ bvt,
    _Float16* El, _Float16* Ep, float (&feat)[4][2][4])
{
    int q = lane >> 4, l15 = lane & 15;
    const u16x8* l0  = (const u16x8*)(Ls + sl.i0 * 32);
    const u16x8* l1  = (const u16x8*)(Ls + sl.i1 * 32);
    const u16x8* p00 = (const u16x8*)(Ps + (sb.i0 * 128 + sa.i0) * 32);
    const u16x8* p01 = (const u16x8*)(Ps + (sb.i0 * 128 + sa.i1) * 32);
    const u16x8* p10 = (const u16x8*)(Ps + (sb.i1 * 128 + sa.i0) * 32);
    const u16x8* p11 = (const u16x8*)(Ps + (sb.i1 * 128 + sa.i1) * 32);
    float w00 = sb.w0 * sa.w0, w01 = sb.w0 * sa.w1;
    float w10 = sb.w1 * sa.w0, w11 = sb.w1 * sa.w1;
#pragma unroll
    for (int cc = 0; cc < 4; ++cc) {
        u16x8 A0 = l0[cc], A1 = l1[cc];
        u16x8 Q00 = p00[cc], Q01 = p01[cc], Q10 = p10[cc], Q11 = p11[cc];
        H8 hl, hp;
#pragma unroll
        for (int kk = 0; kk < 4; ++kk) {
            int k0 = 2 * kk, k1 = k0 + 1;
            float el0 = sl.w0 * bf2f(A0[k0]) + sl.w1 * bf2f(A1[k0]);
            float el1 = sl.w0 * bf2f(A0[k1]) + sl.w1 * bf2f(A1[k1]);
            float ep0 = w00 * bf2f(Q00[k0]) + w01 * bf2f(Q01[k0])
                      + w10 * bf2f(Q10[k0]) + w11 * bf2f(Q11[k0]);
            float ep1 = w00 * bf2f(Q00[k1]) + w01 * bf2f(Q01[k1])
                      + w10 * bf2f(Q10[k1]) + w11 * bf2f(Q11[k1]);
            hl.p[kk] = pk(fmaxf(el0, 0.0f), fmaxf(el1, 0.0f));
            hp.p[kk] = pk(fmaxf(ep0, 0.0f), fmaxf(ep1, 0.0f));
        }
        *(h8v*)&El[lane * SRE + cc * 8] = hl.v;
        *(h8v*)&Ep[lane * SRE + cc * 8] = hp.v;
    }
    __syncthreads();
    h8v bf0 = *(const h8v*)&Wt[(l15) * 32 + q * 8];
    h8v bf1 = *(const h8v*)&Wt[(16 + l15) * 32 + q * 8];
    float bb0 = bvt[l15], bb1 = bvt[16 + l15];
    f4v c0 = {bb0, bb0, bb0, bb0};
    f4v c1 = {bb1, bb1, bb1, bb1};
#pragma unroll
    for (int mt = 0; mt < 4; ++mt) {
        h8v aL = *(const h8v*)&El[(mt * 16 + l15) * SRE + q * 8];
        h8v aP = *(const h8v*)&Ep[(mt * 16 + l15) * SRE + q * 8];
        f4v ta0 = MFMA16(aL, bf0, c0);
        f4v tb0 = MFMA16(aP, bf0, c0);
        f4v ta1 = MFMA16(aL, bf1, c1);
        f4v tb1 = MFMA16(aP, bf1, c1);
#pragma unroll
        for (int r = 0; r < 4; ++r) {
            feat[mt][0][r] += ta0[r] * tb0[r];
            feat[mt][1][r] += ta1[r] * tb1[r];
        }
    }
    __syncthreads();
}

// =====================================================================
// MFMA main — single-wave blocks, XCD-swizzled (grid padded to 8·k),
// coalesced coords
// =====================================================================
__global__ __launch_bounds__(64) void kp_main_mfma(
    const void* __restrict__ coords, const int* __restrict__ order,
    const u16* __restrict__ scoords,
    const u16* __restrict__ planes_s, const u16* __restrict__ vol_s,
    const u16* __restrict__ lines_s,
    const float* __restrict__ wbase,
    void* __restrict__ out, int M)
{
    __shared__ _Float16 eb[5120];   // El[64*40] | Ep[64*40]; reused as E2[64*72]
    __shared__ float res[64];
    int dt = detect_dt(coords);
    const _Float16* WtH = (const _Float16*)wbase;
    const float*    bv  = wbase + 1536;
    const _Float16* W1H = (const _Float16*)(wbase + 1632);
    const float*    b1v = wbase + 5728;
    const float*    W2v = wbase + 5856;
    const float*    b2v = wbase + 5984;

    int lane = threadIdx.x;
    int q = lane >> 4, l15 = lane & 15;
    _Float16* El = eb;
    _Float16* Ep = eb + 2560;
    _Float16* E2 = eb;

    // XCD-aware swizzle; gridDim.x is a multiple of 8 so this is a bijection
    int chunk = gridDim.x >> 3;
    int bsw = (blockIdx.x & 7) * chunk + (blockIdx.x >> 3);

    int p = bsw * 64 + lane;
    p = min(p, M - 1);
    int sp = order[p];

    float x, y, z;
    if (dt == 0) {
        x = bf2f(scoords[p * 3 + 0]);
        y = bf2f(scoords[p * 3 + 1]);
        z = bf2f(scoords[p * 3 + 2]);
    } else {
        x = ((const float*)coords)[sp * 3 + 0];
        y = ((const float*)coords)[sp * 3 + 1];
        z = ((const float*)coords)[sp * 3 + 2];
    }

    Samp sx = make_samp(x, 128), sy = make_samp(y, 128), sz = make_samp(z, 128);

    float feat[4][2][4];
#pragma unroll
    for (int mt = 0; mt < 4; ++mt)
#pragma unroll
        for (int n = 0; n < 2; ++n)
#pragma unroll
            for (int r = 0; r < 4; ++r) feat[mt][n][r] = 0.0f;

    term_mfma(lane, lines_s + 0 * 4096, sx, planes_s + 1 * 524288, sy, sz,
              WtH + 0,    bv + 0,  El, Ep, feat);
    term_mfma(lane, lines_s + 1 * 4096, sy, planes_s + 2 * 524288, sx, sz,
              WtH + 1024, bv + 32, El, Ep, feat);
    term_mfma(lane, lines_s + 2 * 4096, sz, planes_s + 0 * 524288, sx, sy,
              WtH + 2048, bv + 64, El, Ep, feat);

#pragma unroll
    for (int mt = 0; mt < 4; ++mt)
#pragma unroll
        for (int n = 0; n < 2; ++n)
#pragma unroll
            for (int r = 0; r < 4; ++r)
                E2[(mt * 16 + q * 4 + r) * SR2 + n * 16 + l15] =
                    (_Float16)feat[mt][n][r];
    {
        Samp vx = make_samp(x, 64), vy = make_samp(y, 64), vz = make_samp(z, 64);
        float vf[8];
#pragma unroll
        for (int c = 0; c < 8; ++c) vf[c] = 0.0f;
#pragma unroll
        for (int corner = 0; corner < 8; ++corner) {
            int dx = corner & 1, dy = (corner >> 1) & 1, dz = corner >> 2;
            int xi = dx ? vx.i1 : vx.i0;
            int yi = dy ? vy.i1 : vy.i0;
            int zi = dz ? vz.i1 : vz.i0;
            float w = (dx ? vx.w1 : vx.w0) * (dy ? vy.w1 : vy.w0) * (dz ? vz.w1 : vz.w0);
            u16x8 v = *(const u16x8*)(vol_s + (((zi * 64) + yi) * 64 + xi) * 8);
#pragma unroll
            for (int c = 0; c < 8; ++c)
                vf[c] = fmaf(w, bf2f(v[c]), vf[c]);
        }
        H8 hv;
#pragma unroll
        for (int k = 0; k < 4; ++k) hv.p[k] = pk(vf[2 * k], vf[2 * k + 1]);
        *(h8v*)&E2[lane * SR2 + 32] = hv.v;
        h8v zz = {};
        *(h8v*)&E2[lane * SR2 + 40] = zz;
        *(h8v*)&E2[lane * SR2 + 48] = zz;
        *(h8v*)&E2[lane * SR2 + 56] = zz;
    }
    __syncthreads();

    h8v af[4][2];
#pragma unroll
    for (int mt = 0; mt < 4; ++mt)
#pragma unroll
        for (int ks = 0; ks < 2; ++ks)
            af[mt][ks] = *(const h8v*)&E2[(mt * 16 + l15) * SR2 + ks * 32 + q * 8];

    float s[4][4];
#pragma unroll
    for (int mt = 0; mt < 4; ++mt)
#pragma unroll
        for (int r = 0; r < 4; ++r) s[mt][r] = 0.0f;

#pragma unroll
    for (int NT = 0; NT < 8; ++NT) {
        int o = NT * 16 + l15;
        h8v b0 = *(const h8v*)&W1H[o * 64 + q * 8];
        h8v b1f = *(const h8v*)&W1H[o * 64 + 32 + q * 8];
        float w2 = W2v[o];
        float bb = b1v[o];
        f4v cinit = {bb, bb, bb, bb};
#pragma unroll
        for (int mt = 0; mt < 4; ++mt) {
            f4v c = MFMA16(af[mt][0], b0, cinit);
            c = MFMA16(af[mt][1], b1f, c);
#pragma unroll
            for (int r = 0; r < 4; ++r)
                s[mt][r] = fmaf(fmaxf(c[r], 0.0f), w2, s[mt][r]);
        }
    }
#pragma unroll
    for (int mt = 0; mt < 4; ++mt)
#pragma unroll
        for (int r = 0; r < 4; ++r) {
            float v = s[mt][r];
            v += __shfl_xor(v, 1);
            v += __shfl_xor(v, 2);
            v += __shfl_xor(v, 4);
            v += __shfl_xor(v, 8);
            s[mt][r] = v;
        }
    if (l15 == 0) {
#pragma unroll
        for (int mt = 0; mt < 4; ++mt)
#pragma unroll
            for (int r = 0; r < 4; ++r)
                res[mt * 16 + q * 4 + r] = s[mt][r];
    }
    __syncthreads();
    float rr = res[lane] + b2v[0];
    if (dt) ((float*)out)[sp] = rr;
    else    ((u16*)out)[sp] = f2bf(rr);
}

// =====================================================================
// fallback path (ws too small): weights-only prep + direct gathers
// =====================================================================
__global__ void kp_prep_weights_fb(
    const void* __restrict__ coords,
    const void* __restrict__ Wx, const void* __restrict__ bx,
    const void* __restrict__ Wy, const void* __restrict__ by,
    const void* __restrict__ Wz, const void* __restrict__ bz,
    const void* __restrict__ W1, const void* __restrict__ b1,
    const void* __restrict__ W2, const void* __restrict__ b2,
    float* __restrict__ wbase)
{
    int dt = detect_dt(coords);
    int t = blockIdx.x * blockDim.x + threadIdx.x;
    weights_work(dt, t, Wx, bx, Wy, by, Wz, bz, W1, b1, W2, b2, wbase);
}

__global__ __launch_bounds__(256) void kp_main_direct(
    const void* __restrict__ coords,
    const void* __restrict__ lx, const void* __restrict__ ly, const void* __restrict__ lz,
    const void* __restrict__ pxy, const void* __restrict__ pyz, const void* __restrict__ pxz,
    const void* __restrict__ vol,
    const float* __restrict__ wbase,
    void* __restrict__ out, int M)
{
    int dt = detect_dt(coords);
    const _Float16* WtH = (const _Float16*)wbase;
    const float*    bv  = wbase + 1536;
    const _Float16* W1H = (const _Float16*)(wbase + 1632);
    const float*    b1v = wbase + 5728;
    const float*    W2v = wbase + 5856;
    const float*    b2v = wbase + 5984;

    int p = blockIdx.x * 256 + threadIdx.x;
    p = min(p, M - 1);

    float x = gld(dt, coords, p * 3 + 0);
    float y = gld(dt, coords, p * 3 + 1);
    float z = gld(dt, coords, p * 3 + 2);

    Samp sx = make_samp(x, 128), sy = make_samp(y, 128), sz = make_samp(z, 128);

    float feat[40];
#pragma unroll
    for (int o = 0; o < 40; ++o) feat[o] = 0.0f;

    const void* Ls[3] = {lx, ly, lz};
    const void* Psv[3] = {pyz, pxz, pxy};
    Samp sl3[3] = {sx, sy, sz};
    Samp sa3[3] = {sy, sx, sx};
    Samp sb3[3] = {sz, sz, sy};
#pragma unroll 1
    for (int m = 0; m < 3; ++m) {
        float ta[32], tb[32];
        const float* bvt = bv + m * 32;
        const _Float16* Wt = WtH + m * 1024;
#pragma unroll
        for (int o = 0; o < 32; ++o) { ta[o] = bvt[o]; tb[o] = bvt[o]; }
        Samp sl = sl3[m], sa = sa3[m], sb = sb3[m];
        float w00 = sb.w0 * sa.w0, w01 = sb.w0 * sa.w1;
        float w10 = sb.w1 * sa.w0, w11 = sb.w1 * sa.w1;
        int i00 = sb.i0 * 128 + sa.i0, i01 = sb.i0 * 128 + sa.i1;
        int i10 = sb.i1 * 128 + sa.i0, i11 = sb.i1 * 128 + sa.i1;
#pragma unroll 1
        for (int c = 0; c < 32; ++c) {
            float el = sl.w0 * gld(dt, Ls[m], c * 128 + sl.i0)
                     + sl.w1 * gld(dt, Ls[m], c * 128 + sl.i1);
            float ep = w00 * gld(dt, Psv[m], c * 16384 + i00)
                     + w01 * gld(dt, Psv[m], c * 16384 + i01)
                     + w10 * gld(dt, Psv[m], c * 16384 + i10)
                     + w11 * gld(dt, Psv[m], c * 16384 + i11);
            float r1 = fmaxf(el, 0.0f), r2 = fmaxf(ep, 0.0f);
#pragma unroll
            for (int o = 0; o < 32; ++o) {
                float w = (float)Wt[o * 32 + c];
                ta[o] = fmaf(r1, w, ta[o]);
                tb[o] = fmaf(r2, w, tb[o]);
            }
        }
#pragma unroll
        for (int o = 0; o < 32; ++o) feat[o] = fmaf(ta[o], tb[o], feat[o]);
    }

    Samp vx = make_samp(x, 64), vy = make_samp(y, 64), vz = make_samp(z, 64);
#pragma unroll 1
    for (int corner = 0; corner < 8; ++corner) {
        int dx = corner & 1, dy = (corner >> 1) & 1, dz = corner >> 2;
        int xi = dx ? vx.i1 : vx.i0;
        int yi = dy ? vy.i1 : vy.i0;
        int zi = dz ? vz.i1 : vz.i0;
        float w = (dx ? vx.w1 : vx.w0) * (dy ? vy.w1 : vy.w0) * (dz ? vz.w1 : vz.w0);
        int pos = ((zi * 64) + yi) * 64 + xi;
#pragma unroll
        for (int c = 0; c < 8; ++c)
            feat[32 + c] = fmaf(w, gld(dt, vol, c * 262144 + pos), feat[32 + c]);
    }

    float acc_out = b2v[0];
#pragma unroll 2
    for (int j = 0; j < 128; ++j) {
        float acc = b1v[j];
        const _Float16* wr = W1H + j * 64;
#pragma unroll
        for (int i = 0; i < 40; ++i)
            acc = fmaf(feat[i], (float)wr[i], acc);
        acc_out = fmaf(fmaxf(acc, 0.0f), W2v[j], acc_out);
    }
    if (dt) ((float*)out)[p] = acc_out;
    else    ((u16*)out)[p] = f2bf(acc_out);
}

// =====================================================================
extern "C" void kernel_launch(void* const* d_in, const int* in_sizes, int n_in,
                              void* d_out, int out_size, void* d_ws, size_t ws_size,
                              hipStream_t stream) {
    const void* coords = d_in[0];
    const void* lx  = d_in[1];
    const void* ly  = d_in[2];
    const void* lz  = d_in[3];
    const void* pxy = d_in[4];
    const void* pyz = d_in[5];
    const void* pxz = d_in[6];
    const void* vol = d_in[7];
    const void* Wx  = d_in[8];
    const void* bx  = d_in[9];
    const void* Wy  = d_in[10];
    const void* by  = d_in[11];
    const void* Wz  = d_in[12];
    const void* bz  = d_in[13];
    const void* W1  = d_in[14];
    const void* b1  = d_in[15];
    const void* W2  = d_in[16];
    const void* b2  = d_in[17];

    int M = in_sizes[0] / 3;

    char* ws = (char*)d_ws;
    float*        wbase    = (float*)(ws + WF_OFF);
    u16*          planes_s = (u16*)(ws + PLANES_S_OFF);
    u16*          vol_s    = (u16*)(ws + VOL_S_OFF);
    u16*          lines_s  = (u16*)(ws + LINES_S_OFF);
    u16*          part     = (u16*)(ws + PART_OFF);
    unsigned int* tot      = (unsigned int*)(ws + TOT_OFF);
    int*          order    = (int*)(ws + ORDER_OFF);
    u16*          scoords  = (u16*)(ws + ORDER_OFF + (size_t)M * 4u);

    size_t need_sorted = (size_t)ORDER_OFF + (size_t)M * 4u + (size_t)M * 6u;

    if (ws_size >= need_sorted) {
        kp_prep_all<<<2100, 256, 0, stream>>>(coords, lx, ly, lz, pxy, pyz, pxz, vol,
                                              Wx, bx, Wy, by, Wz, bz, W1, b1, W2, b2,
                                              wbase, planes_s, vol_s, lines_s, part, M);
        kp_colscan<<<64, 64, 0, stream>>>(part, tot);
        kp_scatter_det<<<HBLOCKS, 256, 0, stream>>>(coords, part, tot, order,
                                                    scoords, M);
        int blocks64 = (M + 63) / 64;
        blocks64 = (blocks64 + 7) & ~7;     // multiple of 8: swizzle bijection
        kp_main_mfma<<<blocks64, 64, 0, stream>>>(coords, order, scoords,
                                                  planes_s, vol_s,
                                                  lines_s, wbase, d_out, M);
    } else {
        int blocks = (M + 255) / 256;
        kp_prep_weights_fb<<<46, 256, 0, stream>>>(coords, Wx, bx, Wy, by, Wz, bz,
                                                   W1, b1, W2, b2, wbase);
        kp_main_direct<<<blocks, 256, 0, stream>>>(coords, lx, ly, lz, pxy, pyz, pxz,
                                                   vol, wbase, d_out, M);
    }
}

// Round 13
// 200.053 us; speedup vs baseline: 1.6009x; 1.0130x over previous
//
#include <hip/hip_runtime.h>

typedef unsigned short u16;
typedef u16 u16x8 __attribute__((ext_vector_type(8)));
typedef _Float16 half2 __attribute__((ext_vector_type(2)));
typedef _Float16 h8v __attribute__((ext_vector_type(8)));
typedef float f4v __attribute__((ext_vector_type(4)));

union H8 { h8v v; half2 p[4]; };

// ---------- bf16 helpers ----------
static __device__ __forceinline__ float bf2f(u16 u) {
    union { unsigned int i; float f; } v;
    v.i = ((unsigned int)u) << 16;
    return v.f;
}
static __device__ __forceinline__ u16 f2bf(float f) {
    union { float f; unsigned int i; } v;
    v.f = f;
    unsigned int x = v.i;
    x += 0x7fffu + ((x >> 16) & 1u);   // RNE
    return (u16)(x >> 16);
}
static __device__ __forceinline__ float gld(int dt, const void* p, int i) {
    return dt ? ((const float*)p)[i] : bf2f(((const u16*)p)[i]);
}
static __device__ __forceinline__ int detect_dt(const void* coords) {
    u16 v = ((const u16*)coords)[threadIdx.x & 63];
    int e = (v >> 7) & 0xFF;
    bool inr = (e >= 90) && (e <= 126);
    unsigned long long m = __ballot(inr);
    return (__popcll(m) >= 56) ? 0 : 1;   // 0=bf16, 1=f32
}
static __device__ __forceinline__ half2 pk(float a, float b) {
    return __builtin_bit_cast(half2, __builtin_amdgcn_cvt_pkrtz(a, b));
}

// wave-local LDS ordering (single-wave workgroups only): orders LDS ops
// without the full-barrier vmcnt/expcnt drain that __syncthreads implies
static __device__ __forceinline__ void wave_lds_fence() {
    __threadfence_block();
}

// ---------- ws layout (bytes) ----------
#define WF_OFF        64u
#define PLANES_S_OFF  34304u         // 3*524288 u16
#define VOL_S_OFF     3180032u       // 2097152 u16
#define LINES_S_OFF   7374336u       // 12288 u16
#define PART_OFF      7398912u       // 256*4096 u16 = 2 MB
#define TOT_OFF       9496064u       // 4096 u32
#define ORDER_OFF     9512448u       // 4*M
// SCOORD_OFF = ORDER_OFF + 4*M (runtime), 6*M bytes (u16 x3)

#define NBUCK 4096
#define HBLOCKS 256

// weight region (float units from wbase):
//   Wt  f16[3][32 o][32 c]   | bv f32[96] | W1t f16[128][64 pad]
//   b1v f32[128] | W2v f32[128] | b2v f32[1]

// =====================================================================
// spatial key
// =====================================================================
static __device__ __forceinline__ int make_key3(float x, float y, float z) {
    int kx = min(max((int)((x + 1.0f) * 8.0f), 0), 15);
    int ky = min(max((int)((y + 1.0f) * 8.0f), 0), 15);
    int kz = min(max((int)((z + 1.0f) * 8.0f), 0), 15);
    return (kz * 16 + ky) * 16 + kx;
}
static __device__ __forceinline__ int make_key(int dt, const void* coords, int p) {
    return make_key3(gld(dt, coords, p * 3 + 0), gld(dt, coords, p * 3 + 1),
                     gld(dt, coords, p * 3 + 2));
}

// =====================================================================
// weight packing (f16 MFMA layouts)
// =====================================================================
static __device__ __forceinline__ void weights_work(
    int dt, int r,
    const void* Wx, const void* bx, const void* Wy, const void* by,
    const void* Wz, const void* bz, const void* W1, const void* b1,
    const void* W2, const void* b2, float* wbase)
{
    _Float16* WtH = (_Float16*)wbase;
    float*    bv  = wbase + 1536;
    _Float16* W1H = (_Float16*)(wbase + 1632);
    float*    b1v = wbase + 5728;
    float*    W2v = wbase + 5856;
    float*    b2v = wbase + 5984;
    if (r < 3072) {
        int m = r >> 10, idx = r & 1023;
        int o = idx >> 5, c = idx & 31;
        const void* s = (m == 0) ? Wx : (m == 1) ? Wy : Wz;
        WtH[r] = (_Float16)gld(dt, s, c * 32 + o);   // Wt[m][o][c] = W[c][o]
    } else if (r < 3168) {
        int q2 = r - 3072;
        int m = q2 >> 5, c = q2 & 31;
        const void* s = (m == 0) ? bx : (m == 1) ? by : bz;
        bv[q2] = gld(dt, s, c);
    } else if (r < 11360) {
        int idx = r - 3168;                 // j*64 + i
        int j = idx >> 6, i = idx & 63;
        W1H[idx] = (i < 40) ? (_Float16)gld(dt, W1, i * 128 + j) : (_Float16)0.0f;
    } else if (r < 11488) {
        b1v[r - 11360] = gld(dt, b1, r - 11360);
    } else if (r < 11616) {
        W2v[r - 11488] = gld(dt, W2, r - 11488);
    } else if (r == 11616) {
        b2v[0] = gld(dt, b2, 0);
    }
}

// =====================================================================
// fused prep: grid transpose (0..1797) + weights (1798..1843)
//           + histogram partials u16, plain stores (1844..2099)
// =====================================================================
__global__ __launch_bounds__(256) void kp_prep_all(
    const void* __restrict__ coords,
    const void* __restrict__ lx, const void* __restrict__ ly,
    const void* __restrict__ lz,
    const void* __restrict__ pxy, const void* __restrict__ pyz,
    const void* __restrict__ pxz, const void* __restrict__ vol,
    const void* __restrict__ Wx, const void* __restrict__ bx,
    const void* __restrict__ Wy, const void* __restrict__ by,
    const void* __restrict__ Wz, const void* __restrict__ bz,
    const void* __restrict__ W1, const void* __restrict__ b1,
    const void* __restrict__ W2, const void* __restrict__ b2,
    float* __restrict__ wbase,
    u16* __restrict__ planes_s, u16* __restrict__ vol_s,
    u16* __restrict__ lines_s, u16* __restrict__ part, int M)
{
    __shared__ unsigned int lh[NBUCK];
    int dt = detect_dt(coords);
    int blk = blockIdx.x;
    if (blk < 1798) {
        int t = blk * 256 + threadIdx.x;   // [0, 460288)
        u16x8 v;
        if (t < 196608) {                 // planes: 8 consecutive out u16
            int o = t * 8;
            int pl = o >> 19;
            int r  = o & 524287;
            int pos = r >> 5, c0 = r & 31;
            const void* src = (pl == 0) ? pxy : (pl == 1) ? pyz : pxz;
#pragma unroll
            for (int i = 0; i < 8; ++i)
                v[i] = dt ? f2bf(((const float*)src)[(c0 + i) * 16384 + pos])
                          : ((const u16*)src)[(c0 + i) * 16384 + pos];
            *(u16x8*)(planes_s + o) = v;
        } else if (t < 458752) {          // volume: thread = one pos, 8 channels
            int pos = t - 196608;
#pragma unroll
            for (int c = 0; c < 8; ++c)
                v[c] = dt ? f2bf(((const float*)vol)[c * 262144 + pos])
                          : ((const u16*)vol)[c * 262144 + pos];
            *(u16x8*)(vol_s + pos * 8) = v;
        } else {                          // lines
            int o = (t - 458752) * 8;
            int l = o >> 12, rr = o & 4095;
            int pos = rr >> 5, c0 = rr & 31;
            const void* src = (l == 0) ? lx : (l == 1) ? ly : lz;
#pragma unroll
            for (int i = 0; i < 8; ++i)
                v[i] = dt ? f2bf(((const float*)src)[(c0 + i) * 128 + pos])
                          : ((const u16*)src)[(c0 + i) * 128 + pos];
            *(u16x8*)(lines_s + o) = v;
        }
    } else if (blk < 1844) {
        int r = (blk - 1798) * 256 + threadIdx.x;   // [0, 11776)
        weights_work(dt, r, Wx, bx, Wy, by, Wz, bz, W1, b1, W2, b2, wbase);
    } else {
        int b = blk - 1844;               // [0, 256)
        for (int i = threadIdx.x; i < NBUCK; i += 256) lh[i] = 0u;
        __syncthreads();
        for (int p = b * 256 + threadIdx.x; p < M; p += HBLOCKS * 256)
            atomicAdd(&lh[make_key(dt, coords, p)], 1u);
        __syncthreads();
        for (int i = threadIdx.x; i < NBUCK; i += 256)
            part[b * NBUCK + i] = (u16)lh[i];
    }
}

// =====================================================================
// column scan: part[b][bkt] (u16) -> exclusive prefix over b (in place),
// tot[bkt] = column total.
// =====================================================================
__global__ __launch_bounds__(64) void kp_colscan(
    u16* __restrict__ part, unsigned int* __restrict__ tot)
{
    int bkt = blockIdx.x * 64 + threadIdx.x;   // 64 blocks x 64
    unsigned int run = 0;
#pragma unroll 8
    for (int k = 0; k < HBLOCKS; ++k) {
        unsigned int v = part[k * NBUCK + bkt];
        part[k * NBUCK + bkt] = (u16)run;
        run += v;
    }
    tot[bkt] = run;
}

// =====================================================================
// deterministic scatter: 256 blocks, LDS counters, no global atomics.
// Also emits reordered raw-bf16 coords (dt==0) for coalesced main reads.
// =====================================================================
__global__ __launch_bounds__(256) void kp_scatter_det(
    const void* __restrict__ coords, const u16* __restrict__ part,
    const unsigned int* __restrict__ tot,
    int* __restrict__ order, u16* __restrict__ scoords, int M)
{
    __shared__ unsigned int cnt[NBUCK];
    __shared__ unsigned int psum[256];
    int b = blockIdx.x;          // [0, 256)
    int t = threadIdx.x;
    unsigned int bs[16];
    unsigned int s = 0;
#pragma unroll
    for (int i = 0; i < 16; ++i) {
        bs[i] = tot[t * 16 + i];
        s += bs[i];
    }
    psum[t] = s;
    __syncthreads();
    if (t == 0) {
        unsigned int run = 0;
        for (int i = 0; i < 256; ++i) { unsigned int v = psum[i]; psum[i] = run; run += v; }
    }
    __syncthreads();
    unsigned int run = psum[t];
#pragma unroll
    for (int i = 0; i < 16; ++i) {
        int bkt = t * 16 + i;
        cnt[bkt] = run + (unsigned int)part[b * NBUCK + bkt];
        run += bs[i];
    }
    __syncthreads();
    int dt = detect_dt(coords);
    const u16* cu = (const u16*)coords;
    for (int p = b * 256 + t; p < M; p += HBLOCKS * 256) {
        float x = gld(dt, coords, p * 3 + 0);
        float y = gld(dt, coords, p * 3 + 1);
        float z = gld(dt, coords, p * 3 + 2);
        int key = make_key3(x, y, z);
        unsigned int pos = atomicAdd(&cnt[key], 1u);
        order[pos] = p;
        if (dt == 0) {
            scoords[pos * 3 + 0] = cu[p * 3 + 0];
            scoords[pos * 3 + 1] = cu[p * 3 + 1];
            scoords[pos * 3 + 2] = cu[p * 3 + 2];
        }
    }
}

// =====================================================================
// shared math
// =====================================================================
struct Samp { int i0, i1; float w0, w1; };

static __device__ __forceinline__ Samp make_samp(float g, int N) {
    float ix = (g + 1.0f) * 0.5f * (float)(N - 1);
    float fl = floorf(ix);
    float w  = ix - fl;
    int i  = (int)fl;
    int i1 = i + 1;
    float v0 = (i  >= 0 && i  < N) ? 1.0f : 0.0f;
    float v1 = (i1 >= 0 && i1 < N) ? 1.0f : 0.0f;
    Samp s;
    s.w0 = (1.0f - w) * v0;
    s.w1 = w * v1;
    s.i0 = min(max(i, 0), N - 1);
    s.i1 = min(max(i1, 0), N - 1);
    return s;
}

#define MFMA16(a, b, c) __builtin_amdgcn_mfma_f32_16x16x32_f16((a), (b), (c), 0, 0, 0)

#define SRE 40
#define SR2 72

// one product term: interp -> LDS E (f16, relu'd) -> MFMA ta,tb -> feat += ta*tb
// single-wave workgroup: LDS ordering via wave fence (no vmcnt drain)
static __device__ __forceinline__ void term_mfma(
    int lane, const u16* __restrict__ Ls, const Samp& sl,
    const u16* __restrict__ Ps, const Samp& sa, const Samp& sb,
    const _Float16* __restrict__ Wt, const float* __restrict__ bvt,
    _Float16* El, _Float16* Ep, float (&feat)[4][2][4])
{
    int q = lane >> 4, l15 = lane & 15;
    const u16x8* l0  = (const u16x8*)(Ls + sl.i0 * 32);
    const u16x8* l1  = (const u16x8*)(Ls + sl.i1 * 32);
    const u16x8* p00 = (const u16x8*)(Ps + (sb.i0 * 128 + sa.i0) * 32);
    const u16x8* p01 = (const u16x8*)(Ps + (sb.i0 * 128 + sa.i1) * 32);
    const u16x8* p10 = (const u16x8*)(Ps + (sb.i1 * 128 + sa.i0) * 32);
    const u16x8* p11 = (const u16x8*)(Ps + (sb.i1 * 128 + sa.i1) * 32);
    float w00 = sb.w0 * sa.w0, w01 = sb.w0 * sa.w1;
    float w10 = sb.w1 * sa.w0, w11 = sb.w1 * sa.w1;
#pragma unroll
    for (int cc = 0; cc < 4; ++cc) {
        u16x8 A0 = l0[cc], A1 = l1[cc];
        u16x8 Q00 = p00[cc], Q01 = p01[cc], Q10 = p10[cc], Q11 = p11[cc];
        H8 hl, hp;
#pragma unroll
        for (int kk = 0; kk < 4; ++kk) {
            int k0 = 2 * kk, k1 = k0 + 1;
            float el0 = sl.w0 * bf2f(A0[k0]) + sl.w1 * bf2f(A1[k0]);
            float el1 = sl.w0 * bf2f(A0[k1]) + sl.w1 * bf2f(A1[k1]);
            float ep0 = w00 * bf2f(Q00[k0]) + w01 * bf2f(Q01[k0])
                      + w10 * bf2f(Q10[k0]) + w11 * bf2f(Q11[k0]);
            float ep1 = w00 * bf2f(Q00[k1]) + w01 * bf2f(Q01[k1])
                      + w10 * bf2f(Q10[k1]) + w11 * bf2f(Q11[k1]);
            hl.p[kk] = pk(fmaxf(el0, 0.0f), fmaxf(el1, 0.0f));
            hp.p[kk] = pk(fmaxf(ep0, 0.0f), fmaxf(ep1, 0.0f));
        }
        *(h8v*)&El[lane * SRE + cc * 8] = hl.v;
        *(h8v*)&Ep[lane * SRE + cc * 8] = hp.v;
    }
    wave_lds_fence();
    h8v bf0 = *(const h8v*)&Wt[(l15) * 32 + q * 8];
    h8v bf1 = *(const h8v*)&Wt[(16 + l15) * 32 + q * 8];
    float bb0 = bvt[l15], bb1 = bvt[16 + l15];
    f4v c0 = {bb0, bb0, bb0, bb0};
    f4v c1 = {bb1, bb1, bb1, bb1};
#pragma unroll
    for (int mt = 0; mt < 4; ++mt) {
        h8v aL = *(const h8v*)&El[(mt * 16 + l15) * SRE + q * 8];
        h8v aP = *(const h8v*)&Ep[(mt * 16 + l15) * SRE + q * 8];
        f4v ta0 = MFMA16(aL, bf0, c0);
        f4v tb0 = MFMA16(aP, bf0, c0);
        f4v ta1 = MFMA16(aL, bf1, c1);
        f4v tb1 = MFMA16(aP, bf1, c1);
#pragma unroll
        for (int r = 0; r < 4; ++r) {
            feat[mt][0][r] += ta0[r] * tb0[r];
            feat[mt][1][r] += ta1[r] * tb1[r];
        }
    }
    wave_lds_fence();
}

// =====================================================================
// MFMA main — single-wave blocks, natural block order, coalesced coords
// =====================================================================
__global__ __launch_bounds__(64) void kp_main_mfma(
    const void* __restrict__ coords, const int* __restrict__ order,
    const u16* __restrict__ scoords,
    const u16* __restrict__ planes_s, const u16* __restrict__ vol_s,
    const u16* __restrict__ lines_s,
    const float* __restrict__ wbase,
    void* __restrict__ out, int M)
{
    __shared__ _Float16 eb[5120];   // El[64*40] | Ep[64*40]; reused as E2[64*72]
    __shared__ float res[64];
    int dt = detect_dt(coords);
    const _Float16* WtH = (const _Float16*)wbase;
    const float*    bv  = wbase + 1536;
    const _Float16* W1H = (const _Float16*)(wbase + 1632);
    const float*    b1v = wbase + 5728;
    const float*    W2v = wbase + 5856;
    const float*    b2v = wbase + 5984;

    int lane = threadIdx.x;
    int q = lane >> 4, l15 = lane & 15;
    _Float16* El = eb;
    _Float16* Ep = eb + 2560;
    _Float16* E2 = eb;

    int p = blockIdx.x * 64 + lane;
    p = min(p, M - 1);
    int sp = order[p];

    float x, y, z;
    if (dt == 0) {
        x = bf2f(scoords[p * 3 + 0]);
        y = bf2f(scoords[p * 3 + 1]);
        z = bf2f(scoords[p * 3 + 2]);
    } else {
        x = ((const float*)coords)[sp * 3 + 0];
        y = ((const float*)coords)[sp * 3 + 1];
        z = ((const float*)coords)[sp * 3 + 2];
    }

    Samp sx = make_samp(x, 128), sy = make_samp(y, 128), sz = make_samp(z, 128);

    float feat[4][2][4];
#pragma unroll
    for (int mt = 0; mt < 4; ++mt)
#pragma unroll
        for (int n = 0; n < 2; ++n)
#pragma unroll
            for (int r = 0; r < 4; ++r) feat[mt][n][r] = 0.0f;

    term_mfma(lane, lines_s + 0 * 4096, sx, planes_s + 1 * 524288, sy, sz,
              WtH + 0,    bv + 0,  El, Ep, feat);
    term_mfma(lane, lines_s + 1 * 4096, sy, planes_s + 2 * 524288, sx, sz,
              WtH + 1024, bv + 32, El, Ep, feat);
    term_mfma(lane, lines_s + 2 * 4096, sz, planes_s + 0 * 524288, sx, sy,
              WtH + 2048, bv + 64, El, Ep, feat);

#pragma unroll
    for (int mt = 0; mt < 4; ++mt)
#pragma unroll
        for (int n = 0; n < 2; ++n)
#pragma unroll
            for (int r = 0; r < 4; ++r)
                E2[(mt * 16 + q * 4 + r) * SR2 + n * 16 + l15] =
                    (_Float16)feat[mt][n][r];
    {
        Samp vx = make_samp(x, 64), vy = make_samp(y, 64), vz = make_samp(z, 64);
        float vf[8];
#pragma unroll
        for (int c = 0; c < 8; ++c) vf[c] = 0.0f;
#pragma unroll
        for (int corner = 0; corner < 8; ++corner) {
            int dx = corner & 1, dy = (corner >> 1) & 1, dz = corner >> 2;
            int xi = dx ? vx.i1 : vx.i0;
            int yi = dy ? vy.i1 : vy.i0;
            int zi = dz ? vz.i1 : vz.i0;
            float w = (dx ? vx.w1 : vx.w0) * (dy ? vy.w1 : vy.w0) * (dz ? vz.w1 : vz.w0);
            u16x8 v = *(const u16x8*)(vol_s + (((zi * 64) + yi) * 64 + xi) * 8);
#pragma unroll
            for (int c = 0; c < 8; ++c)
                vf[c] = fmaf(w, bf2f(v[c]), vf[c]);
        }
        H8 hv;
#pragma unroll
        for (int k = 0; k < 4; ++k) hv.p[k] = pk(vf[2 * k], vf[2 * k + 1]);
        *(h8v*)&E2[lane * SR2 + 32] = hv.v;
        h8v zz = {};
        *(h8v*)&E2[lane * SR2 + 40] = zz;
        *(h8v*)&E2[lane * SR2 + 48] = zz;
        *(h8v*)&E2[lane * SR2 + 56] = zz;
    }
    wave_lds_fence();

    h8v af[4][2];
#pragma unroll
    for (int mt = 0; mt < 4; ++mt)
#pragma unroll
        for (int ks = 0; ks < 2; ++ks)
            af[mt][ks] = *(const h8v*)&E2[(mt * 16 + l15) * SR2 + ks * 32 + q * 8];

    float s[4][4];
#pragma unroll
    for (int mt = 0; mt < 4; ++mt)
#pragma unroll
        for (int r = 0; r < 4; ++r) s[mt][r] = 0.0f;

#pragma unroll
    for (int NT = 0; NT < 8; ++NT) {
        int o = NT * 16 + l15;
        h8v b0 = *(const h8v*)&W1H[o * 64 + q * 8];
        h8v b1f = *(const h8v*)&W1H[o * 64 + 32 + q * 8];
        float w2 = W2v[o];
        float bb = b1v[o];
        f4v cinit = {bb, bb, bb, bb};
#pragma unroll
        for (int mt = 0; mt < 4; ++mt) {
            f4v c = MFMA16(af[mt][0], b0, cinit);
            c = MFMA16(af[mt][1], b1f, c);
#pragma unroll
            for (int r = 0; r < 4; ++r)
                s[mt][r] = fmaf(fmaxf(c[r], 0.0f), w2, s[mt][r]);
        }
    }
#pragma unroll
    for (int mt = 0; mt < 4; ++mt)
#pragma unroll
        for (int r = 0; r < 4; ++r) {
            float v = s[mt][r];
            v += __shfl_xor(v, 1);
            v += __shfl_xor(v, 2);
            v += __shfl_xor(v, 4);
            v += __shfl_xor(v, 8);
            s[mt][r] = v;
        }
    if (l15 == 0) {
#pragma unroll
        for (int mt = 0; mt < 4; ++mt)
#pragma unroll
            for (int r = 0; r < 4; ++r)
                res[mt * 16 + q * 4 + r] = s[mt][r];
    }
    wave_lds_fence();
    float rr = res[lane] + b2v[0];
    if (dt) ((float*)out)[sp] = rr;
    else    ((u16*)out)[sp] = f2bf(rr);
}

// =====================================================================
// fallback path (ws too small): weights-only prep + direct gathers
// =====================================================================
__global__ void kp_prep_weights_fb(
    const void* __restrict__ coords,
    const void* __restrict__ Wx, const void* __restrict__ bx,
    const void* __restrict__ Wy, const void* __restrict__ by,
    const void* __restrict__ Wz, const void* __restrict__ bz,
    const void* __restrict__ W1, const void* __restrict__ b1,
    const void* __restrict__ W2, const void* __restrict__ b2,
    float* __restrict__ wbase)
{
    int dt = detect_dt(coords);
    int t = blockIdx.x * blockDim.x + threadIdx.x;
    weights_work(dt, t, Wx, bx, Wy, by, Wz, bz, W1, b1, W2, b2, wbase);
}

__global__ __launch_bounds__(256) void kp_main_direct(
    const void* __restrict__ coords,
    const void* __restrict__ lx, const void* __restrict__ ly, const void* __restrict__ lz,
    const void* __restrict__ pxy, const void* __restrict__ pyz, const void* __restrict__ pxz,
    const void* __restrict__ vol,
    const float* __restrict__ wbase,
    void* __restrict__ out, int M)
{
    int dt = detect_dt(coords);
    const _Float16* WtH = (const _Float16*)wbase;
    const float*    bv  = wbase + 1536;
    const _Float16* W1H = (const _Float16*)(wbase + 1632);
    const float*    b1v = wbase + 5728;
    const float*    W2v = wbase + 5856;
    const float*    b2v = wbase + 5984;

    int p = blockIdx.x * 256 + threadIdx.x;
    p = min(p, M - 1);

    float x = gld(dt, coords, p * 3 + 0);
    float y = gld(dt, coords, p * 3 + 1);
    float z = gld(dt, coords, p * 3 + 2);

    Samp sx = make_samp(x, 128), sy = make_samp(y, 128), sz = make_samp(z, 128);

    float feat[40];
#pragma unroll
    for (int o = 0; o < 40; ++o) feat[o] = 0.0f;

    const void* Ls[3] = {lx, ly, lz};
    const void* Psv[3] = {pyz, pxz, pxy};
    Samp sl3[3] = {sx, sy, sz};
    Samp sa3[3] = {sy, sx, sx};
    Samp sb3[3] = {sz, sz, sy};
#pragma unroll 1
    for (int m = 0; m < 3; ++m) {
        float ta[32], tb[32];
        const float* bvt = bv + m * 32;
        const _Float16* Wt = WtH + m * 1024;
#pragma unroll
        for (int o = 0; o < 32; ++o) { ta[o] = bvt[o]; tb[o] = bvt[o]; }
        Samp sl = sl3[m], sa = sa3[m], sb = sb3[m];
        float w00 = sb.w0 * sa.w0, w01 = sb.w0 * sa.w1;
        float w10 = sb.w1 * sa.w0, w11 = sb.w1 * sa.w1;
        int i00 = sb.i0 * 128 + sa.i0, i01 = sb.i0 * 128 + sa.i1;
        int i10 = sb.i1 * 128 + sa.i0, i11 = sb.i1 * 128 + sa.i1;
#pragma unroll 1
        for (int c = 0; c < 32; ++c) {
            float el = sl.w0 * gld(dt, Ls[m], c * 128 + sl.i0)
                     + sl.w1 * gld(dt, Ls[m], c * 128 + sl.i1);
            float ep = w00 * gld(dt, Psv[m], c * 16384 + i00)
                     + w01 * gld(dt, Psv[m], c * 16384 + i01)
                     + w10 * gld(dt, Psv[m], c * 16384 + i10)
                     + w11 * gld(dt, Psv[m], c * 16384 + i11);
            float r1 = fmaxf(el, 0.0f), r2 = fmaxf(ep, 0.0f);
#pragma unroll
            for (int o = 0; o < 32; ++o) {
                float w = (float)Wt[o * 32 + c];
                ta[o] = fmaf(r1, w, ta[o]);
                tb[o] = fmaf(r2, w, tb[o]);
            }
        }
#pragma unroll
        for (int o = 0; o < 32; ++o) feat[o] = fmaf(ta[o], tb[o], feat[o]);
    }

    Samp vx = make_samp(x, 64), vy = make_samp(y, 64), vz = make_samp(z, 64);
#pragma unroll 1
    for (int corner = 0; corner < 8; ++corner) {
        int dx = corner & 1, dy = (corner >> 1) & 1, dz = corner >> 2;
        int xi = dx ? vx.i1 : vx.i0;
        int yi = dy ? vy.i1 : vy.i0;
        int zi = dz ? vz.i1 : vz.i0;
        float w = (dx ? vx.w1 : vx.w0) * (dy ? vy.w1 : vy.w0) * (dz ? vz.w1 : vz.w0);
        int pos = ((zi * 64) + yi) * 64 + xi;
#pragma unroll
        for (int c = 0; c < 8; ++c)
            feat[32 + c] = fmaf(w, gld(dt, vol, c * 262144 + pos), feat[32 + c]);
    }

    float acc_out = b2v[0];
#pragma unroll 2
    for (int j = 0; j < 128; ++j) {
        float acc = b1v[j];
        const _Float16* wr = W1H + j * 64;
#pragma unroll
        for (int i = 0; i < 40; ++i)
            acc = fmaf(feat[i], (float)wr[i], acc);
        acc_out = fmaf(fmaxf(acc, 0.0f), W2v[j], acc_out);
    }
    if (dt) ((float*)out)[p] = acc_out;
    else    ((u16*)out)[p] = f2bf(acc_out);
}

// =====================================================================
extern "C" void kernel_launch(void* const* d_in, const int* in_sizes, int n_in,
                              void* d_out, int out_size, void* d_ws, size_t ws_size,
                              hipStream_t stream) {
    const void* coords = d_in[0];
    const void* lx  = d_in[1];
    const void* ly  = d_in[2];
    const void* lz  = d_in[3];
    const void* pxy = d_in[4];
    const void* pyz = d_in[5];
    const void* pxz = d_in[6];
    const void* vol = d_in[7];
    const void* Wx  = d_in[8];
    const void* bx  = d_in[9];
    const void* Wy  = d_in[10];
    const void* by  = d_in[11];
    const void* Wz  = d_in[12];
    const void* bz  = d_in[13];
    const void* W1  = d_in[14];
    const void* b1  = d_in[15];
    const void* W2  = d_in[16];
    const void* b2  = d_in[17];

    int M = in_sizes[0] / 3;

    char* ws = (char*)d_ws;
    float*        wbase    = (float*)(ws + WF_OFF);
    u16*          planes_s = (u16*)(ws + PLANES_S_OFF);
    u16*          vol_s    = (u16*)(ws + VOL_S_OFF);
    u16*          lines_s  = (u16*)(ws + LINES_S_OFF);
    u16*          part     = (u16*)(ws + PART_OFF);
    unsigned int* tot      = (unsigned int*)(ws + TOT_OFF);
    int*          order    = (int*)(ws + ORDER_OFF);
    u16*          scoords  = (u16*)(ws + ORDER_OFF + (size_t)M * 4u);

    size_t need_sorted = (size_t)ORDER_OFF + (size_t)M * 4u + (size_t)M * 6u;

    if (ws_size >= need_sorted) {
        kp_prep_all<<<2100, 256, 0, stream>>>(coords, lx, ly, lz, pxy, pyz, pxz, vol,
                                              Wx, bx, Wy, by, Wz, bz, W1, b1, W2, b2,
                                              wbase, planes_s, vol_s, lines_s, part, M);
        kp_colscan<<<64, 64, 0, stream>>>(part, tot);
        kp_scatter_det<<<HBLOCKS, 256, 0, stream>>>(coords, part, tot, order,
                                                    scoords, M);
        int blocks64 = (M + 63) / 64;
        kp_main_mfma<<<blocks64, 64, 0, stream>>>(coords, order, scoords,
                                                  planes_s, vol_s,
                                                  lines_s, wbase, d_out, M);
    } else {
        int blocks = (M + 255) / 256;
        kp_prep_weights_fb<<<46, 256, 0, stream>>>(coords, Wx, bx, Wy, by, Wz, bz,
                                                   W1, b1, W2, b2, wbase);
        kp_main_direct<<<blocks, 256, 0, stream>>>(coords, lx, ly, lz, pxy, pyz, pxz,
                                                   vol, wbase, d_out, M);
    }
}